// Round 8
// baseline (643.156 us; speedup 1.0000x reference)
//
#include <hip/hip_runtime.h>
#include <hip/hip_bf16.h>
#include <math.h>

// ---------------------------------------------------------------------------
// ActorGNN: 4-layer GraphConv. R8:
//  - fill: XCD-affine via s_getreg(HW_REG_XCC_ID) + per-range atomic tickets
//    with work-stealing (coverage guaranteed even if XCC_ID is wrong).
//    R7's blockIdx&7 partition still had all 8 XCDs dirtying each col line
//    (WRITE_SIZE 72MB for 6.4MB payload); physical-XCD ranges make each line
//    single-L2-owned -> written back once.
//  - dropped agg lo-path (Glo): agg already carries gather's bf16 row error,
//    so the Glo*Bhi refinement term is below the noise floor. Saves
//    12.8MB/layer write + read and 2/12 MFMAs. H stays hi/lo 3-term.
// ---------------------------------------------------------------------------

using bfrag = __attribute__((ext_vector_type(8))) short;   // 8 bf16 (4 VGPR)
using ffrag = __attribute__((ext_vector_type(4))) float;   // 4 fp32 acc

__device__ __forceinline__ int load_idx32(const int* __restrict__ ei32, int is64,
                                          long long pos) {
    return is64 ? ei32[2 * pos] : ei32[pos];
}

__device__ __forceinline__ unsigned short f2b_rne(float f) {
    union { float f; unsigned u; } c;
    c.f = f;
    unsigned r = c.u + 0x7FFFu + ((c.u >> 16) & 1u);
    return (unsigned short)(r >> 16);
}

__device__ __forceinline__ float b2f(unsigned short u) {
    union { unsigned u; float f; } c;
    c.u = ((unsigned)u) << 16;
    return c.f;
}

// physical XCD id (gfx940+: HW_REG_XCC_ID = 20; simm16 = size-1<<11|off<<6|id)
__device__ __forceinline__ int xcc_id() {
    return (int)(__builtin_amdgcn_s_getreg((3u << 11) | (0u << 6) | 20u) & 7u);
}

// int64 vs int32 edge_index detection (int64 values < 2^31 => odd words zero)
__global__ void detect_idx_kernel(const int* __restrict__ ei, int* __restrict__ flag) {
    int allz = 1;
    for (int i = 0; i < 32; ++i)
        if (ei[2 * i + 1] != 0) allz = 0;
    *flag = allz;
}

__global__ void zero_int_kernel(int* __restrict__ p, int n) {
    int i = blockIdx.x * blockDim.x + threadIdx.x;
    if (i < n) p[i] = 0;
}

__global__ void hist_kernel(const int* __restrict__ ei32, const int* __restrict__ flagp,
                            int* __restrict__ degi, int E) {
    int e = blockIdx.x * blockDim.x + threadIdx.x;
    if (e >= E) return;
    int is64 = *flagp;
    int dst = load_idx32(ei32, is64, (long long)E + e);
    atomicAdd(&degi[dst], 1);
}

// exclusive scan over degi -> off, 1024 elems/block, block sums -> bsum
__global__ __launch_bounds__(256) void scanA_kernel(const int* __restrict__ degi,
                                                    int* __restrict__ off,
                                                    int* __restrict__ bsum, int N) {
    __shared__ int lds[256];
    int t = threadIdx.x;
    int base = blockIdx.x * 1024 + t * 4;
    int d[4];
#pragma unroll
    for (int i = 0; i < 4; ++i) d[i] = (base + i < N) ? degi[base + i] : 0;
    int s = d[0] + d[1] + d[2] + d[3];
    lds[t] = s;
    __syncthreads();
    for (int o = 1; o < 256; o <<= 1) {
        int v = (t >= o) ? lds[t - o] : 0;
        __syncthreads();
        lds[t] += v;
        __syncthreads();
    }
    int excl = lds[t] - s;
    if (t == 255) bsum[blockIdx.x] = lds[255];
    int p = excl;
#pragma unroll
    for (int i = 0; i < 4; ++i) {
        if (base + i < N) off[base + i] = p;
        p += d[i];
    }
}

__global__ __launch_bounds__(1024) void scanB_kernel(int* __restrict__ bsum, int B) {
    __shared__ int lds[1024];
    int t = threadIdx.x;
    int s = (t < B) ? bsum[t] : 0;
    lds[t] = s;
    __syncthreads();
    for (int o = 1; o < 1024; o <<= 1) {
        int v = (t >= o) ? lds[t - o] : 0;
        __syncthreads();
        lds[t] += v;
        __syncthreads();
    }
    if (t < B) bsum[t] = lds[t] - s;
}

__global__ void scanC_kernel(int* __restrict__ off, const int* __restrict__ bsum, int N) {
    int i = blockIdx.x * blockDim.x + threadIdx.x;
    if (i < N) off[i] += bsum[i >> 10];
}

__global__ void copy_int_kernel(int* __restrict__ dstp, const int* __restrict__ srcp, int n) {
    int i = blockIdx.x * blockDim.x + threadIdx.x;
    if (i < n) dstp[i] = srcp[i];
}

// XCD-affine CSR fill. Block prefers the dst-range == its physical XCD id,
// claiming edge segments via per-range tickets; steals other ranges when its
// own is exhausted (coverage independent of XCC_ID correctness).
// Afterwards cur[n] == off[n] + deg[n] (used as `end`).
#define FILL_NSEG 256
__global__ __launch_bounds__(256) void fill_kernel(const int* __restrict__ ei32,
                                                   const int* __restrict__ flagp,
                                                   int* __restrict__ cur,
                                                   int* __restrict__ col,
                                                   int* __restrict__ ticket, int E) {
    __shared__ int s_seg;
    int is64 = *flagp;
    int r0 = xcc_id();
    int segsz = (E + FILL_NSEG - 1) / FILL_NSEG;
    for (int rr = 0; rr < 8; ++rr) {
        int r = (r0 + rr) & 7;
        while (true) {
            if (threadIdx.x == 0) s_seg = atomicAdd(&ticket[r], 1);
            __syncthreads();
            int seg = s_seg;
            __syncthreads();
            if (seg >= FILL_NSEG) break;
            int elo = seg * segsz;
            int ehi = min(E, elo + segsz);
            for (int e = elo + (int)threadIdx.x; e < ehi; e += 256) {
                int dst = load_idx32(ei32, is64, (long long)E + e);
                if ((int)(((unsigned)dst * 41u) >> 19) == r) {
                    int src = load_idx32(ei32, is64, e);
                    int pos = atomicAdd(&cur[dst], 1);
                    col[pos] = src;
                }
            }
        }
    }
}

__global__ void deginv_kernel(const int* __restrict__ degi, float* __restrict__ dinv, int N) {
    int n = blockIdx.x * blockDim.x + threadIdx.x;
    if (n < N) dinv[n] = 1.0f / fmaxf((float)degi[n], 1.0f);
}

// x -> (hi, lo) bf16 split, [n][d] layout preserved
__global__ void split_x_kernel(const float4* __restrict__ in, ushort4* __restrict__ hi,
                               ushort4* __restrict__ lo, int n4) {
    int i = blockIdx.x * blockDim.x + threadIdx.x;
    if (i >= n4) return;
    float4 v = in[i];
    ushort4 h, l;
    h.x = f2b_rne(v.x); l.x = f2b_rne(v.x - b2f(h.x));
    h.y = f2b_rne(v.y); l.y = f2b_rne(v.y - b2f(h.y));
    h.z = f2b_rne(v.z); l.z = f2b_rne(v.z - b2f(h.z));
    h.w = f2b_rne(v.w); l.w = f2b_rne(v.w - b2f(h.w));
    hi[i] = h;
    lo[i] = l;
}

// Build B^T hi/lo for one layer: Bt[n][k], k 0..63 from Ws, 64..127 from Wn.
__global__ void bprep_kernel(const float* __restrict__ Ws, const float* __restrict__ Wn,
                             unsigned short* __restrict__ bthi,
                             unsigned short* __restrict__ btlo) {
    int i = blockIdx.x * blockDim.x + threadIdx.x;
    if (i >= 64 * 128) return;
    int n = i >> 7, k = i & 127;
    float v = (k < 64) ? Ws[k * 64 + n] : Wn[(k - 64) * 64 + n];
    unsigned short hi = f2b_rne(v);
    bthi[i] = hi;
    btlo[i] = f2b_rne(v - b2f(hi));
}

// wave per node; lane = g*16 + t: edge-group g (0..3), dims t*4..t*4+3.
// Reads bf16-hi rows (128B); emits mean-scaled agg as bf16 hi only.
__global__ __launch_bounds__(256) void gather64_b16_kernel(
    const unsigned short* __restrict__ hb, const int* __restrict__ off,
    const int* __restrict__ endp, const int* __restrict__ col,
    const float* __restrict__ dinv, unsigned short* __restrict__ ghi, int N) {
    int wave = threadIdx.x >> 6;
    int lane = threadIdx.x & 63;
    int g = lane >> 4;
    int t = lane & 15;
    int n = blockIdx.x * 4 + wave;
    if (n >= N) return;
    int e = off[n], end = endp[n];
    float4 a0 = make_float4(0.f, 0.f, 0.f, 0.f);
    float4 a1 = make_float4(0.f, 0.f, 0.f, 0.f);
    float4 a2 = make_float4(0.f, 0.f, 0.f, 0.f);
    float4 a3 = make_float4(0.f, 0.f, 0.f, 0.f);
    for (; e + 16 <= end; e += 16) {
        int s0 = col[e + g];
        int s1 = col[e + 4 + g];
        int s2 = col[e + 8 + g];
        int s3 = col[e + 12 + g];
        ushort4 u0 = *(const ushort4*)&hb[(size_t)s0 * 64 + t * 4];
        ushort4 u1 = *(const ushort4*)&hb[(size_t)s1 * 64 + t * 4];
        ushort4 u2 = *(const ushort4*)&hb[(size_t)s2 * 64 + t * 4];
        ushort4 u3 = *(const ushort4*)&hb[(size_t)s3 * 64 + t * 4];
        a0.x += b2f(u0.x); a0.y += b2f(u0.y); a0.z += b2f(u0.z); a0.w += b2f(u0.w);
        a1.x += b2f(u1.x); a1.y += b2f(u1.y); a1.z += b2f(u1.z); a1.w += b2f(u1.w);
        a2.x += b2f(u2.x); a2.y += b2f(u2.y); a2.z += b2f(u2.z); a2.w += b2f(u2.w);
        a3.x += b2f(u3.x); a3.y += b2f(u3.y); a3.z += b2f(u3.z); a3.w += b2f(u3.w);
    }
    for (; e + 8 <= end; e += 8) {
        int s0 = col[e + g];
        int s1 = col[e + 4 + g];
        ushort4 u0 = *(const ushort4*)&hb[(size_t)s0 * 64 + t * 4];
        ushort4 u1 = *(const ushort4*)&hb[(size_t)s1 * 64 + t * 4];
        a0.x += b2f(u0.x); a0.y += b2f(u0.y); a0.z += b2f(u0.z); a0.w += b2f(u0.w);
        a1.x += b2f(u1.x); a1.y += b2f(u1.y); a1.z += b2f(u1.z); a1.w += b2f(u1.w);
    }
    for (; e < end; e += 4) {
        if (e + g < end) {
            int s0 = col[e + g];
            ushort4 u0 = *(const ushort4*)&hb[(size_t)s0 * 64 + t * 4];
            a2.x += b2f(u0.x); a2.y += b2f(u0.y); a2.z += b2f(u0.z); a2.w += b2f(u0.w);
        }
    }
    float4 acc;
    acc.x = (a0.x + a1.x) + (a2.x + a3.x);
    acc.y = (a0.y + a1.y) + (a2.y + a3.y);
    acc.z = (a0.z + a1.z) + (a2.z + a3.z);
    acc.w = (a0.w + a1.w) + (a2.w + a3.w);
#pragma unroll
    for (int m = 16; m <= 32; m <<= 1) {
        acc.x += __shfl_xor(acc.x, m, 64);
        acc.y += __shfl_xor(acc.y, m, 64);
        acc.z += __shfl_xor(acc.z, m, 64);
        acc.w += __shfl_xor(acc.w, m, 64);
    }
    if (g == 0) {
        float di = dinv[n];
        ushort4 h;
        h.x = f2b_rne(acc.x * di);
        h.y = f2b_rne(acc.y * di);
        h.z = f2b_rne(acc.z * di);
        h.w = f2b_rne(acc.w * di);
        *(ushort4*)&ghi[(size_t)n * 64 + t * 4] = h;
    }
}

// MFMA dense: out = relu([h|agg] @ [Ws;Wn] + b). H is hi/lo (3-term split);
// G (agg) is hi-only (2-term: Ghi*Bhi + Ghi*Blo).
// A-frag: m=lane&15, k=quad*8+j. B-frag: n=lane&15 (Bt[n][k]).
// C/D: col=lane&15 (out dim), row=quad*4+reg (node). Emits hi/lo bf16.
__global__ __launch_bounds__(256) void dense_mfma_kernel(
    const unsigned short* __restrict__ Hhi, const unsigned short* __restrict__ Hlo,
    const unsigned short* __restrict__ Ghi,
    const unsigned short* __restrict__ Bthi, const unsigned short* __restrict__ Btlo,
    const float* __restrict__ b, unsigned short* __restrict__ Dhi,
    unsigned short* __restrict__ Dlo, int N) {
    int lane = threadIdx.x & 63;
    int m = lane & 15, quad = lane >> 4;
    int wid = (blockIdx.x * blockDim.x + threadIdx.x) >> 6;
    int nw = (gridDim.x * blockDim.x) >> 6;
    bfrag bhi[4][4];
#pragma unroll
    for (int t = 0; t < 4; ++t)
#pragma unroll
        for (int c = 0; c < 4; ++c)
            bhi[t][c] = *(const bfrag*)(Bthi + (size_t)(t * 16 + m) * 128 + c * 32 + quad * 8);
    float bl[4];
#pragma unroll
    for (int t = 0; t < 4; ++t) bl[t] = b[t * 16 + m];
    int ngroups = (N + 15) >> 4;
    for (int g = wid; g < ngroups; g += nw) {
        int n0 = g << 4;
        int nr = n0 + m;
        if (nr > N - 1) nr = N - 1;
        const unsigned short* hrow = Hhi + (size_t)nr * 64 + quad * 8;
        const unsigned short* lrow = Hlo + (size_t)nr * 64 + quad * 8;
        const unsigned short* grow = Ghi + (size_t)nr * 64 + quad * 8;
        bfrag ah[4], al[2];
        ah[0] = *(const bfrag*)(hrow);
        ah[1] = *(const bfrag*)(hrow + 32);
        ah[2] = *(const bfrag*)(grow);
        ah[3] = *(const bfrag*)(grow + 32);
        al[0] = *(const bfrag*)(lrow);
        al[1] = *(const bfrag*)(lrow + 32);
#pragma unroll
        for (int t = 0; t < 4; ++t) {
            ffrag acc = {bl[t], bl[t], bl[t], bl[t]};
#pragma unroll
            for (int c = 0; c < 4; ++c) {
                bfrag blo = *(const bfrag*)(Btlo + (size_t)(t * 16 + m) * 128 + c * 32 + quad * 8);
                acc = __builtin_amdgcn_mfma_f32_16x16x32_bf16(ah[c], bhi[t][c], acc, 0, 0, 0);
                if (c < 2)
                    acc = __builtin_amdgcn_mfma_f32_16x16x32_bf16(al[c], bhi[t][c], acc, 0, 0, 0);
                acc = __builtin_amdgcn_mfma_f32_16x16x32_bf16(ah[c], blo, acc, 0, 0, 0);
            }
#pragma unroll
            for (int r = 0; r < 4; ++r) {
                int node = n0 + quad * 4 + r;
                if (node < N) {
                    float v = fmaxf(acc[r], 0.f);
                    unsigned short hi = f2b_rne(v);
                    Dhi[(size_t)node * 64 + t * 16 + m] = hi;
                    Dlo[(size_t)node * 64 + t * 16 + m] = f2b_rne(v - b2f(hi));
                }
            }
        }
    }
}

// layer-4 pre-transform: s[n]=h[n,:]·Ws4, g[n]=h[n,:]·Wn4 (64->1); h = hi+lo
__global__ __launch_bounds__(256) void layer4_pre_kernel(
    const unsigned short* __restrict__ Hhi, const unsigned short* __restrict__ Hlo,
    const float* __restrict__ Ws, const float* __restrict__ Wn,
    float* __restrict__ s, float* __restrict__ g, int N) {
    int wave = threadIdx.x >> 6;
    int lane = threadIdx.x & 63;
    int n = blockIdx.x * 4 + wave;
    if (n >= N) return;
    float hv = b2f(Hhi[(size_t)n * 64 + lane]) + b2f(Hlo[(size_t)n * 64 + lane]);
    float vs = hv * Ws[lane];
    float vn = hv * Wn[lane];
#pragma unroll
    for (int o = 32; o > 0; o >>= 1) {
        vs += __shfl_down(vs, o, 64);
        vn += __shfl_down(vn, o, 64);
    }
    if (lane == 0) {
        s[n] = vs;
        g[n] = vn;
    }
}

// thread per node: scalar CSR gather of g (400 KB, L2-resident) + sigmoid
__global__ void final_kernel(const float* __restrict__ s, const float* __restrict__ dinv,
                             const float* __restrict__ g, const int* __restrict__ off,
                             const int* __restrict__ endp, const int* __restrict__ col,
                             const float* __restrict__ b4, float* __restrict__ out, int N) {
    int n = blockIdx.x * blockDim.x + threadIdx.x;
    if (n >= N) return;
    float a = 0.f;
    int e = off[n], end = endp[n];
    for (; e < end; ++e) a += g[col[e]];
    float z = s[n] + dinv[n] * a + b4[0];
    out[n] = 1.0f / (1.0f + expf(-z));
}

static inline int cdiv(long long a, long long b) { return (int)((a + b - 1) / b); }

extern "C" void kernel_launch(void* const* d_in, const int* in_sizes, int n_in,
                              void* d_out, int out_size, void* d_ws, size_t ws_size,
                              hipStream_t stream) {
    const float* x   = (const float*)d_in[0];
    const int*   ei  = (const int*)d_in[1];
    const float* Ws1 = (const float*)d_in[2];
    const float* Wn1 = (const float*)d_in[3];
    const float* b1  = (const float*)d_in[4];
    const float* Ws2 = (const float*)d_in[5];
    const float* Wn2 = (const float*)d_in[6];
    const float* b2  = (const float*)d_in[7];
    const float* Ws3 = (const float*)d_in[8];
    const float* Wn3 = (const float*)d_in[9];
    const float* b3  = (const float*)d_in[10];
    const float* Ws4 = (const float*)d_in[11];
    const float* Wn4 = (const float*)d_in[12];
    const float* b4  = (const float*)d_in[13];
    float* out = (float*)d_out;

    const int N = in_sizes[0] / 64;
    const int E = in_sizes[1] / 2;

    // workspace layout
    unsigned short* HhiA = (unsigned short*)d_ws;        // N*64
    unsigned short* HloA = HhiA + (size_t)N * 64;        // N*64
    unsigned short* HhiB = HloA + (size_t)N * 64;        // N*64
    unsigned short* HloB = HhiB + (size_t)N * 64;        // N*64
    unsigned short* Ghi  = HloB + (size_t)N * 64;        // N*64
    unsigned short* Bth  = Ghi + (size_t)N * 64;         // 3*8192
    unsigned short* Btl  = Bth + 3 * 8192;               // 3*8192
    float* dinv = (float*)(Btl + 3 * 8192);              // N
    float* sbuf = dinv + N;                              // N
    float* gbuf = sbuf + N;                              // N
    int*   degi = (int*)(gbuf + N);                      // N
    int*   tick = degi + N;                              // 8
    int*   off  = tick + 8;                              // N
    int*   curp = off + N;                               // N
    int*   col  = curp + N;                              // E
    int*   bsum = col + E;                               // 1024
    int*   flag = bsum + 1024;                           // 1

    const int BT = 256;
    const int gridN  = cdiv(N, BT);
    const int gridE  = cdiv(E, BT);
    const int gridNd = cdiv(N, 4);
    const int gridMM = cdiv(cdiv(N, 16), 4);  // 4 waves/block, 1 group/wave
    const int gridFill = 1280;
    const int B      = cdiv(N, 1024);

    detect_idx_kernel<<<1, 1, 0, stream>>>(ei, flag);

    // ---- CSR build (once; edges are layer-invariant) ----
    zero_int_kernel<<<cdiv(N + 8, BT), BT, 0, stream>>>(degi, N + 8);  // degi + tickets
    hist_kernel<<<gridE, BT, 0, stream>>>(ei, flag, degi, E);
    scanA_kernel<<<B, 256, 0, stream>>>(degi, off, bsum, N);
    scanB_kernel<<<1, 1024, 0, stream>>>(bsum, B);
    scanC_kernel<<<gridN, BT, 0, stream>>>(off, bsum, N);
    copy_int_kernel<<<gridN, BT, 0, stream>>>(curp, off, N);
    fill_kernel<<<gridFill, BT, 0, stream>>>(ei, flag, curp, col, tick, E);
    deginv_kernel<<<gridN, BT, 0, stream>>>(degi, dinv, N);

    // ---- weight prep (B^T hi/lo per layer) + x split ----
    bprep_kernel<<<32, BT, 0, stream>>>(Ws1, Wn1, Bth, Btl);
    bprep_kernel<<<32, BT, 0, stream>>>(Ws2, Wn2, Bth + 8192, Btl + 8192);
    bprep_kernel<<<32, BT, 0, stream>>>(Ws3, Wn3, Bth + 16384, Btl + 16384);
    split_x_kernel<<<cdiv((long long)N * 16, BT), BT, 0, stream>>>(
        (const float4*)x, (ushort4*)HhiA, (ushort4*)HloA, N * 16);

    // ---- layer 1: pairA -> pairB ----
    gather64_b16_kernel<<<gridNd, BT, 0, stream>>>(HhiA, off, curp, col, dinv, Ghi, N);
    dense_mfma_kernel<<<gridMM, BT, 0, stream>>>(HhiA, HloA, Ghi, Bth, Btl, b1,
                                                 HhiB, HloB, N);

    // ---- layer 2: pairB -> pairA ----
    gather64_b16_kernel<<<gridNd, BT, 0, stream>>>(HhiB, off, curp, col, dinv, Ghi, N);
    dense_mfma_kernel<<<gridMM, BT, 0, stream>>>(HhiB, HloB, Ghi, Bth + 8192,
                                                 Btl + 8192, b2, HhiA, HloA, N);

    // ---- layer 3: pairA -> pairB ----
    gather64_b16_kernel<<<gridNd, BT, 0, stream>>>(HhiA, off, curp, col, dinv, Ghi, N);
    dense_mfma_kernel<<<gridMM, BT, 0, stream>>>(HhiA, HloA, Ghi, Bth + 16384,
                                                 Btl + 16384, b3, HhiB, HloB, N);

    // ---- layer 4 (64->1): pre-transform then scalar CSR gather + sigmoid ----
    layer4_pre_kernel<<<gridNd, BT, 0, stream>>>(HhiB, HloB, Ws4, Wn4, sbuf, gbuf, N);
    final_kernel<<<gridN, BT, 0, stream>>>(sbuf, dinv, gbuf, off, curp, col, b4, out, N);
}

// Round 9
// 463.373 us; speedup vs baseline: 1.3880x; 1.3880x over previous
//
#include <hip/hip_runtime.h>
#include <hip/hip_bf16.h>
#include <math.h>

// ---------------------------------------------------------------------------
// ActorGNN: 4-layer GraphConv. R9:
//  - CSR build rewritten as a 3-pass counting sort (bin -> degree -> scatter).
//    R3..R8 fills all suffered ~11x write amplification: a node's ~16 edges
//    arrive from random blocks across all 8 XCDs, so every 64B col line was
//    dirtied by ~7 L2s. PassC gives each bucket (512 nodes, ~32KB col) to ONE
//    block -> one L2 owner -> lines written back once. PassA's binned writes
//    are compact per-block runs (line-dense). Replaces hist+copy+fill.
//  - dense: MFMA split-bf16 (H hi/lo 3-term, agg hi-only) - R8's version.
//  - gather: bf16 rows, 16 in flight, hi-only agg output - R8's version.
// ---------------------------------------------------------------------------

using bfrag = __attribute__((ext_vector_type(8))) short;   // 8 bf16 (4 VGPR)
using ffrag = __attribute__((ext_vector_type(4))) float;   // 4 fp32 acc

#define BKT_SHIFT 9                 // 512 nodes per bucket (N<=131072 -> <=256 buckets)
#define BKT_NODES (1 << BKT_SHIFT)

__device__ __forceinline__ int load_idx32(const int* __restrict__ ei32, int is64,
                                          long long pos) {
    return is64 ? ei32[2 * pos] : ei32[pos];
}

__device__ __forceinline__ unsigned short f2b_rne(float f) {
    union { float f; unsigned u; } c;
    c.f = f;
    unsigned r = c.u + 0x7FFFu + ((c.u >> 16) & 1u);
    return (unsigned short)(r >> 16);
}

__device__ __forceinline__ float b2f(unsigned short u) {
    union { unsigned u; float f; } c;
    c.u = ((unsigned)u) << 16;
    return c.f;
}

// int64 vs int32 edge_index detection (int64 values < 2^31 => odd words zero)
__global__ void detect_idx_kernel(const int* __restrict__ ei, int* __restrict__ flag) {
    int allz = 1;
    for (int i = 0; i < 32; ++i)
        if (ei[2 * i + 1] != 0) allz = 0;
    *flag = allz;
}

__global__ void zero_int_kernel(int* __restrict__ p, int n) {
    int i = blockIdx.x * blockDim.x + threadIdx.x;
    if (i < n) p[i] = 0;
}

// ---- PassA: bin edges into dst-buckets as compact (src,dst) runs ----
__global__ __launch_bounds__(256) void binA_kernel(
    const int* __restrict__ ei32, const int* __restrict__ flagp,
    int* __restrict__ bktCnt, uint2* __restrict__ bins, int E, int nbkt,
    int cap, int chunksz) {
    __shared__ int cnt[256];
    __shared__ int base[256];
    int is64 = *flagp;
    int elo = blockIdx.x * chunksz;
    int ehi = min(E, elo + chunksz);
    if (elo >= E) return;
    for (int i = threadIdx.x; i < nbkt; i += 256) cnt[i] = 0;
    __syncthreads();
    for (int e = elo + (int)threadIdx.x; e < ehi; e += 256) {
        int dst = load_idx32(ei32, is64, (long long)E + e);
        atomicAdd(&cnt[dst >> BKT_SHIFT], 1);
    }
    __syncthreads();
    for (int i = threadIdx.x; i < nbkt; i += 256) {
        base[i] = atomicAdd(&bktCnt[i], cnt[i]);
        cnt[i] = 0;
    }
    __syncthreads();
    for (int e = elo + (int)threadIdx.x; e < ehi; e += 256) {
        int dst = load_idx32(ei32, is64, (long long)E + e);
        int src = load_idx32(ei32, is64, e);
        int b = dst >> BKT_SHIFT;
        int r = atomicAdd(&cnt[b], 1);
        bins[(size_t)b * cap + base[b] + r] = make_uint2((unsigned)src, (unsigned)dst);
    }
}

// ---- PassB: per-bucket degree histogram via LDS ----
__global__ __launch_bounds__(256) void degB_kernel(
    const int* __restrict__ bktCnt, const uint2* __restrict__ bins,
    int* __restrict__ degi, int N, int cap) {
    __shared__ int dcnt[BKT_NODES];
    int b = blockIdx.x;
    int lo = b << BKT_SHIFT;
    int n = min(BKT_NODES, N - lo);
    for (int i = threadIdx.x; i < n; i += 256) dcnt[i] = 0;
    __syncthreads();
    int cnt = bktCnt[b];
    const uint2* bb = bins + (size_t)b * cap;
    for (int i = threadIdx.x; i < cnt; i += 256)
        atomicAdd(&dcnt[bb[i].y - lo], 1);
    __syncthreads();
    for (int i = threadIdx.x; i < n; i += 256) degi[lo + i] = dcnt[i];
}

// exclusive scan over degi -> off, 1024 elems/block, block sums -> bsum
__global__ __launch_bounds__(256) void scanA_kernel(const int* __restrict__ degi,
                                                    int* __restrict__ off,
                                                    int* __restrict__ bsum, int N) {
    __shared__ int lds[256];
    int t = threadIdx.x;
    int base = blockIdx.x * 1024 + t * 4;
    int d[4];
#pragma unroll
    for (int i = 0; i < 4; ++i) d[i] = (base + i < N) ? degi[base + i] : 0;
    int s = d[0] + d[1] + d[2] + d[3];
    lds[t] = s;
    __syncthreads();
    for (int o = 1; o < 256; o <<= 1) {
        int v = (t >= o) ? lds[t - o] : 0;
        __syncthreads();
        lds[t] += v;
        __syncthreads();
    }
    int excl = lds[t] - s;
    if (t == 255) bsum[blockIdx.x] = lds[255];
    int p = excl;
#pragma unroll
    for (int i = 0; i < 4; ++i) {
        if (base + i < N) off[base + i] = p;
        p += d[i];
    }
}

__global__ __launch_bounds__(1024) void scanB_kernel(int* __restrict__ bsum, int B) {
    __shared__ int lds[1024];
    int t = threadIdx.x;
    int s = (t < B) ? bsum[t] : 0;
    lds[t] = s;
    __syncthreads();
    for (int o = 1; o < 1024; o <<= 1) {
        int v = (t >= o) ? lds[t - o] : 0;
        __syncthreads();
        lds[t] += v;
        __syncthreads();
    }
    if (t < B) bsum[t] = lds[t] - s;
}

__global__ void scanC_kernel(int* __restrict__ off, const int* __restrict__ bsum, int N) {
    int i = blockIdx.x * blockDim.x + threadIdx.x;
    if (i < N) off[i] += bsum[i >> 10];
}

// ---- PassC: per-bucket scatter into col; cur in LDS; emits curp (ends) ----
__global__ __launch_bounds__(256) void scatC_kernel(
    const int* __restrict__ bktCnt, const uint2* __restrict__ bins,
    const int* __restrict__ off, int* __restrict__ col,
    int* __restrict__ curp, int N, int cap) {
    __shared__ int cur[BKT_NODES];
    int b = blockIdx.x;
    int lo = b << BKT_SHIFT;
    int n = min(BKT_NODES, N - lo);
    for (int i = threadIdx.x; i < n; i += 256) cur[i] = off[lo + i];
    __syncthreads();
    int cnt = bktCnt[b];
    const uint2* bb = bins + (size_t)b * cap;
    for (int i = threadIdx.x; i < cnt; i += 256) {
        uint2 u = bb[i];
        int pos = atomicAdd(&cur[u.y - lo], 1);
        col[pos] = (int)u.x;
    }
    __syncthreads();
    for (int i = threadIdx.x; i < n; i += 256) curp[lo + i] = cur[i];
}

__global__ void deginv_kernel(const int* __restrict__ degi, float* __restrict__ dinv, int N) {
    int n = blockIdx.x * blockDim.x + threadIdx.x;
    if (n < N) dinv[n] = 1.0f / fmaxf((float)degi[n], 1.0f);
}

// x -> (hi, lo) bf16 split, [n][d] layout preserved
__global__ void split_x_kernel(const float4* __restrict__ in, ushort4* __restrict__ hi,
                               ushort4* __restrict__ lo, int n4) {
    int i = blockIdx.x * blockDim.x + threadIdx.x;
    if (i >= n4) return;
    float4 v = in[i];
    ushort4 h, l;
    h.x = f2b_rne(v.x); l.x = f2b_rne(v.x - b2f(h.x));
    h.y = f2b_rne(v.y); l.y = f2b_rne(v.y - b2f(h.y));
    h.z = f2b_rne(v.z); l.z = f2b_rne(v.z - b2f(h.z));
    h.w = f2b_rne(v.w); l.w = f2b_rne(v.w - b2f(h.w));
    hi[i] = h;
    lo[i] = l;
}

// Build B^T hi/lo for one layer: Bt[n][k], k 0..63 from Ws, 64..127 from Wn.
__global__ void bprep_kernel(const float* __restrict__ Ws, const float* __restrict__ Wn,
                             unsigned short* __restrict__ bthi,
                             unsigned short* __restrict__ btlo) {
    int i = blockIdx.x * blockDim.x + threadIdx.x;
    if (i >= 64 * 128) return;
    int n = i >> 7, k = i & 127;
    float v = (k < 64) ? Ws[k * 64 + n] : Wn[(k - 64) * 64 + n];
    unsigned short hi = f2b_rne(v);
    bthi[i] = hi;
    btlo[i] = f2b_rne(v - b2f(hi));
}

// wave per node; lane = g*16 + t: edge-group g (0..3), dims t*4..t*4+3.
// Reads bf16-hi rows (128B); emits mean-scaled agg as bf16 hi only.
__global__ __launch_bounds__(256) void gather64_b16_kernel(
    const unsigned short* __restrict__ hb, const int* __restrict__ off,
    const int* __restrict__ endp, const int* __restrict__ col,
    const float* __restrict__ dinv, unsigned short* __restrict__ ghi, int N) {
    int wave = threadIdx.x >> 6;
    int lane = threadIdx.x & 63;
    int g = lane >> 4;
    int t = lane & 15;
    int n = blockIdx.x * 4 + wave;
    if (n >= N) return;
    int e = off[n], end = endp[n];
    float4 a0 = make_float4(0.f, 0.f, 0.f, 0.f);
    float4 a1 = make_float4(0.f, 0.f, 0.f, 0.f);
    float4 a2 = make_float4(0.f, 0.f, 0.f, 0.f);
    float4 a3 = make_float4(0.f, 0.f, 0.f, 0.f);
    for (; e + 16 <= end; e += 16) {
        int s0 = col[e + g];
        int s1 = col[e + 4 + g];
        int s2 = col[e + 8 + g];
        int s3 = col[e + 12 + g];
        ushort4 u0 = *(const ushort4*)&hb[(size_t)s0 * 64 + t * 4];
        ushort4 u1 = *(const ushort4*)&hb[(size_t)s1 * 64 + t * 4];
        ushort4 u2 = *(const ushort4*)&hb[(size_t)s2 * 64 + t * 4];
        ushort4 u3 = *(const ushort4*)&hb[(size_t)s3 * 64 + t * 4];
        a0.x += b2f(u0.x); a0.y += b2f(u0.y); a0.z += b2f(u0.z); a0.w += b2f(u0.w);
        a1.x += b2f(u1.x); a1.y += b2f(u1.y); a1.z += b2f(u1.z); a1.w += b2f(u1.w);
        a2.x += b2f(u2.x); a2.y += b2f(u2.y); a2.z += b2f(u2.z); a2.w += b2f(u2.w);
        a3.x += b2f(u3.x); a3.y += b2f(u3.y); a3.z += b2f(u3.z); a3.w += b2f(u3.w);
    }
    for (; e + 8 <= end; e += 8) {
        int s0 = col[e + g];
        int s1 = col[e + 4 + g];
        ushort4 u0 = *(const ushort4*)&hb[(size_t)s0 * 64 + t * 4];
        ushort4 u1 = *(const ushort4*)&hb[(size_t)s1 * 64 + t * 4];
        a0.x += b2f(u0.x); a0.y += b2f(u0.y); a0.z += b2f(u0.z); a0.w += b2f(u0.w);
        a1.x += b2f(u1.x); a1.y += b2f(u1.y); a1.z += b2f(u1.z); a1.w += b2f(u1.w);
    }
    for (; e < end; e += 4) {
        if (e + g < end) {
            int s0 = col[e + g];
            ushort4 u0 = *(const ushort4*)&hb[(size_t)s0 * 64 + t * 4];
            a2.x += b2f(u0.x); a2.y += b2f(u0.y); a2.z += b2f(u0.z); a2.w += b2f(u0.w);
        }
    }
    float4 acc;
    acc.x = (a0.x + a1.x) + (a2.x + a3.x);
    acc.y = (a0.y + a1.y) + (a2.y + a3.y);
    acc.z = (a0.z + a1.z) + (a2.z + a3.z);
    acc.w = (a0.w + a1.w) + (a2.w + a3.w);
#pragma unroll
    for (int m = 16; m <= 32; m <<= 1) {
        acc.x += __shfl_xor(acc.x, m, 64);
        acc.y += __shfl_xor(acc.y, m, 64);
        acc.z += __shfl_xor(acc.z, m, 64);
        acc.w += __shfl_xor(acc.w, m, 64);
    }
    if (g == 0) {
        float di = dinv[n];
        ushort4 h;
        h.x = f2b_rne(acc.x * di);
        h.y = f2b_rne(acc.y * di);
        h.z = f2b_rne(acc.z * di);
        h.w = f2b_rne(acc.w * di);
        *(ushort4*)&ghi[(size_t)n * 64 + t * 4] = h;
    }
}

// MFMA dense: out = relu([h|agg] @ [Ws;Wn] + b). H is hi/lo (3-term split);
// G (agg) is hi-only (2-term). A-frag: m=lane&15, k=quad*8+j. B-frag:
// n=lane&15 (Bt[n][k]). C/D: col=lane&15, row=quad*4+reg. Emits hi/lo bf16.
__global__ __launch_bounds__(256) void dense_mfma_kernel(
    const unsigned short* __restrict__ Hhi, const unsigned short* __restrict__ Hlo,
    const unsigned short* __restrict__ Ghi,
    const unsigned short* __restrict__ Bthi, const unsigned short* __restrict__ Btlo,
    const float* __restrict__ b, unsigned short* __restrict__ Dhi,
    unsigned short* __restrict__ Dlo, int N) {
    int lane = threadIdx.x & 63;
    int m = lane & 15, quad = lane >> 4;
    int wid = (blockIdx.x * blockDim.x + threadIdx.x) >> 6;
    int nw = (gridDim.x * blockDim.x) >> 6;
    bfrag bhi[4][4];
#pragma unroll
    for (int t = 0; t < 4; ++t)
#pragma unroll
        for (int c = 0; c < 4; ++c)
            bhi[t][c] = *(const bfrag*)(Bthi + (size_t)(t * 16 + m) * 128 + c * 32 + quad * 8);
    float bl[4];
#pragma unroll
    for (int t = 0; t < 4; ++t) bl[t] = b[t * 16 + m];
    int ngroups = (N + 15) >> 4;
    for (int g = wid; g < ngroups; g += nw) {
        int n0 = g << 4;
        int nr = n0 + m;
        if (nr > N - 1) nr = N - 1;
        const unsigned short* hrow = Hhi + (size_t)nr * 64 + quad * 8;
        const unsigned short* lrow = Hlo + (size_t)nr * 64 + quad * 8;
        const unsigned short* grow = Ghi + (size_t)nr * 64 + quad * 8;
        bfrag ah[4], al[2];
        ah[0] = *(const bfrag*)(hrow);
        ah[1] = *(const bfrag*)(hrow + 32);
        ah[2] = *(const bfrag*)(grow);
        ah[3] = *(const bfrag*)(grow + 32);
        al[0] = *(const bfrag*)(lrow);
        al[1] = *(const bfrag*)(lrow + 32);
#pragma unroll
        for (int t = 0; t < 4; ++t) {
            ffrag acc = {bl[t], bl[t], bl[t], bl[t]};
#pragma unroll
            for (int c = 0; c < 4; ++c) {
                bfrag blo = *(const bfrag*)(Btlo + (size_t)(t * 16 + m) * 128 + c * 32 + quad * 8);
                acc = __builtin_amdgcn_mfma_f32_16x16x32_bf16(ah[c], bhi[t][c], acc, 0, 0, 0);
                if (c < 2)
                    acc = __builtin_amdgcn_mfma_f32_16x16x32_bf16(al[c], bhi[t][c], acc, 0, 0, 0);
                acc = __builtin_amdgcn_mfma_f32_16x16x32_bf16(ah[c], blo, acc, 0, 0, 0);
            }
#pragma unroll
            for (int r = 0; r < 4; ++r) {
                int node = n0 + quad * 4 + r;
                if (node < N) {
                    float v = fmaxf(acc[r], 0.f);
                    unsigned short hi = f2b_rne(v);
                    Dhi[(size_t)node * 64 + t * 16 + m] = hi;
                    Dlo[(size_t)node * 64 + t * 16 + m] = f2b_rne(v - b2f(hi));
                }
            }
        }
    }
}

// layer-4 pre-transform: s[n]=h[n,:]·Ws4, g[n]=h[n,:]·Wn4 (64->1); h = hi+lo
__global__ __launch_bounds__(256) void layer4_pre_kernel(
    const unsigned short* __restrict__ Hhi, const unsigned short* __restrict__ Hlo,
    const float* __restrict__ Ws, const float* __restrict__ Wn,
    float* __restrict__ s, float* __restrict__ g, int N) {
    int wave = threadIdx.x >> 6;
    int lane = threadIdx.x & 63;
    int n = blockIdx.x * 4 + wave;
    if (n >= N) return;
    float hv = b2f(Hhi[(size_t)n * 64 + lane]) + b2f(Hlo[(size_t)n * 64 + lane]);
    float vs = hv * Ws[lane];
    float vn = hv * Wn[lane];
#pragma unroll
    for (int o = 32; o > 0; o >>= 1) {
        vs += __shfl_down(vs, o, 64);
        vn += __shfl_down(vn, o, 64);
    }
    if (lane == 0) {
        s[n] = vs;
        g[n] = vn;
    }
}

// thread per node: scalar CSR gather of g (400 KB, L2-resident) + sigmoid
__global__ void final_kernel(const float* __restrict__ s, const float* __restrict__ dinv,
                             const float* __restrict__ g, const int* __restrict__ off,
                             const int* __restrict__ endp, const int* __restrict__ col,
                             const float* __restrict__ b4, float* __restrict__ out, int N) {
    int n = blockIdx.x * blockDim.x + threadIdx.x;
    if (n >= N) return;
    float a = 0.f;
    int e = off[n], end = endp[n];
    for (; e < end; ++e) a += g[col[e]];
    float z = s[n] + dinv[n] * a + b4[0];
    out[n] = 1.0f / (1.0f + expf(-z));
}

static inline int cdiv(long long a, long long b) { return (int)((a + b - 1) / b); }

extern "C" void kernel_launch(void* const* d_in, const int* in_sizes, int n_in,
                              void* d_out, int out_size, void* d_ws, size_t ws_size,
                              hipStream_t stream) {
    const float* x   = (const float*)d_in[0];
    const int*   ei  = (const int*)d_in[1];
    const float* Ws1 = (const float*)d_in[2];
    const float* Wn1 = (const float*)d_in[3];
    const float* b1  = (const float*)d_in[4];
    const float* Ws2 = (const float*)d_in[5];
    const float* Wn2 = (const float*)d_in[6];
    const float* b2  = (const float*)d_in[7];
    const float* Ws3 = (const float*)d_in[8];
    const float* Wn3 = (const float*)d_in[9];
    const float* b3  = (const float*)d_in[10];
    const float* Ws4 = (const float*)d_in[11];
    const float* Wn4 = (const float*)d_in[12];
    const float* b4  = (const float*)d_in[13];
    float* out = (float*)d_out;

    const int N = in_sizes[0] / 64;
    const int E = in_sizes[1] / 2;

    const int nbkt = cdiv(N, BKT_NODES);                 // <=256 for N<=131072
    const int cap  = E / nbkt + E / nbkt / 8 + 64;       // ~12.5% margin

    // workspace layout (bins first: 8B alignment)
    uint2* bins = (uint2*)d_ws;                          // nbkt*cap
    unsigned short* HhiA = (unsigned short*)(bins + (size_t)nbkt * cap);
    unsigned short* HloA = HhiA + (size_t)N * 64;
    unsigned short* HhiB = HloA + (size_t)N * 64;
    unsigned short* HloB = HhiB + (size_t)N * 64;
    unsigned short* Ghi  = HloB + (size_t)N * 64;
    unsigned short* Bth  = Ghi + (size_t)N * 64;         // 3*8192
    unsigned short* Btl  = Bth + 3 * 8192;               // 3*8192
    float* dinv = (float*)(Btl + 3 * 8192);              // N
    float* sbuf = dinv + N;                              // N
    float* gbuf = sbuf + N;                              // N
    int*   degi = (int*)(gbuf + N);                      // N
    int*   off  = degi + N;                              // N
    int*   curp = off + N;                               // N
    int*   col  = curp + N;                              // E
    int*   bsum = col + E;                               // 1024
    int*   bktc = bsum + 1024;                           // 256
    int*   flag = bktc + 256;                            // 1

    const int BT = 256;
    const int gridN  = cdiv(N, BT);
    const int gridNd = cdiv(N, 4);
    const int gridMM = cdiv(cdiv(N, 16), 4);
    const int B      = cdiv(N, 1024);
    const int binBlocks = 512;
    const int chunksz = cdiv(E, binBlocks);

    detect_idx_kernel<<<1, 1, 0, stream>>>(ei, flag);

    // ---- CSR build: counting sort (bin -> degree -> scan -> scatter) ----
    zero_int_kernel<<<1, BT, 0, stream>>>(bktc, 256);
    binA_kernel<<<binBlocks, BT, 0, stream>>>(ei, flag, bktc, bins, E, nbkt, cap, chunksz);
    degB_kernel<<<nbkt, BT, 0, stream>>>(bktc, bins, degi, N, cap);
    scanA_kernel<<<B, 256, 0, stream>>>(degi, off, bsum, N);
    scanB_kernel<<<1, 1024, 0, stream>>>(bsum, B);
    scanC_kernel<<<gridN, BT, 0, stream>>>(off, bsum, N);
    scatC_kernel<<<nbkt, BT, 0, stream>>>(bktc, bins, off, col, curp, N, cap);
    deginv_kernel<<<gridN, BT, 0, stream>>>(degi, dinv, N);

    // ---- weight prep (B^T hi/lo per layer) + x split ----
    bprep_kernel<<<32, BT, 0, stream>>>(Ws1, Wn1, Bth, Btl);
    bprep_kernel<<<32, BT, 0, stream>>>(Ws2, Wn2, Bth + 8192, Btl + 8192);
    bprep_kernel<<<32, BT, 0, stream>>>(Ws3, Wn3, Bth + 16384, Btl + 16384);
    split_x_kernel<<<cdiv((long long)N * 16, BT), BT, 0, stream>>>(
        (const float4*)x, (ushort4*)HhiA, (ushort4*)HloA, N * 16);

    // ---- layer 1: pairA -> pairB ----
    gather64_b16_kernel<<<gridNd, BT, 0, stream>>>(HhiA, off, curp, col, dinv, Ghi, N);
    dense_mfma_kernel<<<gridMM, BT, 0, stream>>>(HhiA, HloA, Ghi, Bth, Btl, b1,
                                                 HhiB, HloB, N);

    // ---- layer 2: pairB -> pairA ----
    gather64_b16_kernel<<<gridNd, BT, 0, stream>>>(HhiB, off, curp, col, dinv, Ghi, N);
    dense_mfma_kernel<<<gridMM, BT, 0, stream>>>(HhiB, HloB, Ghi, Bth + 8192,
                                                 Btl + 8192, b2, HhiA, HloA, N);

    // ---- layer 3: pairA -> pairB ----
    gather64_b16_kernel<<<gridNd, BT, 0, stream>>>(HhiA, off, curp, col, dinv, Ghi, N);
    dense_mfma_kernel<<<gridMM, BT, 0, stream>>>(HhiA, HloA, Ghi, Bth + 16384,
                                                 Btl + 16384, b3, HhiB, HloB, N);

    // ---- layer 4 (64->1): pre-transform then scalar CSR gather + sigmoid ----
    layer4_pre_kernel<<<gridNd, BT, 0, stream>>>(HhiB, HloB, Ws4, Wn4, sbuf, gbuf, N);
    final_kernel<<<gridN, BT, 0, stream>>>(sbuf, dinv, gbuf, off, curp, col, b4, out, N);
}

// Round 10
// 427.020 us; speedup vs baseline: 1.5061x; 1.0851x over previous
//
#include <hip/hip_runtime.h>
#include <hip/hip_bf16.h>
#include <math.h>

// ---------------------------------------------------------------------------
// ActorGNN: 4-layer GraphConv. R10:
//  - gather held at R9 form (near structural floor: 8 XCD x 12.8MB L2-dedup
//    ~= 102MB EA traffic vs 152 observed; no mechanism found for the rest).
//  - dense3 fuses the layer-4 pre-transform: s,g computed from fp32 accs via
//    intra-quad shfl reduction -> l4pre kernel + layer-3 D writes eliminated.
//  - h state hi-only after layer 1 (weights stay hi/lo split; x keeps full
//    split): -64MB traffic, absmax budget 2 ulp.
//  - CSR: off[N+1] (end = off[n+1], curp dropped), dinv fused into degB,
//    bprep 3-in-1, detect+zero fused. 17 dispatches.
// ---------------------------------------------------------------------------

using bfrag = __attribute__((ext_vector_type(8))) short;   // 8 bf16 (4 VGPR)
using ffrag = __attribute__((ext_vector_type(4))) float;   // 4 fp32 acc

#define BKT_SHIFT 9                 // 512 nodes per bucket
#define BKT_NODES (1 << BKT_SHIFT)

__device__ __forceinline__ int load_idx32(const int* __restrict__ ei32, int is64,
                                          long long pos) {
    return is64 ? ei32[2 * pos] : ei32[pos];
}

__device__ __forceinline__ unsigned short f2b_rne(float f) {
    union { float f; unsigned u; } c;
    c.f = f;
    unsigned r = c.u + 0x7FFFu + ((c.u >> 16) & 1u);
    return (unsigned short)(r >> 16);
}

__device__ __forceinline__ float b2f(unsigned short u) {
    union { unsigned u; float f; } c;
    c.u = ((unsigned)u) << 16;
    return c.f;
}

// zero bucket counters + int64-vs-int32 detection in one launch
__global__ void init_kernel(const int* __restrict__ ei, int* __restrict__ bktc,
                            int* __restrict__ flag) {
    bktc[threadIdx.x] = 0;
    if (threadIdx.x == 0) {
        int allz = 1;
        for (int i = 0; i < 32; ++i)
            if (ei[2 * i + 1] != 0) allz = 0;
        *flag = allz;
    }
}

// ---- PassA: bin edges into dst-buckets as compact (src,dst) runs ----
__global__ __launch_bounds__(256) void binA_kernel(
    const int* __restrict__ ei32, const int* __restrict__ flagp,
    int* __restrict__ bktCnt, uint2* __restrict__ bins, int E, int nbkt,
    int cap, int chunksz) {
    __shared__ int cnt[256];
    __shared__ int base[256];
    int is64 = *flagp;
    int elo = blockIdx.x * chunksz;
    int ehi = min(E, elo + chunksz);
    if (elo >= E) return;
    for (int i = threadIdx.x; i < nbkt; i += 256) cnt[i] = 0;
    __syncthreads();
    for (int e = elo + (int)threadIdx.x; e < ehi; e += 256) {
        int dst = load_idx32(ei32, is64, (long long)E + e);
        atomicAdd(&cnt[dst >> BKT_SHIFT], 1);
    }
    __syncthreads();
    for (int i = threadIdx.x; i < nbkt; i += 256) {
        base[i] = atomicAdd(&bktCnt[i], cnt[i]);
        cnt[i] = 0;
    }
    __syncthreads();
    for (int e = elo + (int)threadIdx.x; e < ehi; e += 256) {
        int dst = load_idx32(ei32, is64, (long long)E + e);
        int src = load_idx32(ei32, is64, e);
        int b = dst >> BKT_SHIFT;
        int r = atomicAdd(&cnt[b], 1);
        bins[(size_t)b * cap + base[b] + r] = make_uint2((unsigned)src, (unsigned)dst);
    }
}

// ---- PassB: per-bucket degree histogram via LDS; also emits dinv ----
__global__ __launch_bounds__(256) void degB_kernel(
    const int* __restrict__ bktCnt, const uint2* __restrict__ bins,
    int* __restrict__ degi, float* __restrict__ dinv, int N, int cap) {
    __shared__ int dcnt[BKT_NODES];
    int b = blockIdx.x;
    int lo = b << BKT_SHIFT;
    int n = min(BKT_NODES, N - lo);
    for (int i = threadIdx.x; i < n; i += 256) dcnt[i] = 0;
    __syncthreads();
    int cnt = bktCnt[b];
    const uint2* bb = bins + (size_t)b * cap;
    for (int i = threadIdx.x; i < cnt; i += 256)
        atomicAdd(&dcnt[bb[i].y - lo], 1);
    __syncthreads();
    for (int i = threadIdx.x; i < n; i += 256) {
        int d = dcnt[i];
        degi[lo + i] = d;
        dinv[lo + i] = 1.0f / fmaxf((float)d, 1.0f);
    }
}

// exclusive scan over degi -> off, 1024 elems/block, block sums -> bsum
__global__ __launch_bounds__(256) void scanA_kernel(const int* __restrict__ degi,
                                                    int* __restrict__ off,
                                                    int* __restrict__ bsum, int N) {
    __shared__ int lds[256];
    int t = threadIdx.x;
    int base = blockIdx.x * 1024 + t * 4;
    int d[4];
#pragma unroll
    for (int i = 0; i < 4; ++i) d[i] = (base + i < N) ? degi[base + i] : 0;
    int s = d[0] + d[1] + d[2] + d[3];
    lds[t] = s;
    __syncthreads();
    for (int o = 1; o < 256; o <<= 1) {
        int v = (t >= o) ? lds[t - o] : 0;
        __syncthreads();
        lds[t] += v;
        __syncthreads();
    }
    int excl = lds[t] - s;
    if (t == 255) bsum[blockIdx.x] = lds[255];
    int p = excl;
#pragma unroll
    for (int i = 0; i < 4; ++i) {
        if (base + i < N) off[base + i] = p;
        p += d[i];
    }
}

__global__ __launch_bounds__(1024) void scanB_kernel(int* __restrict__ bsum, int B) {
    __shared__ int lds[1024];
    int t = threadIdx.x;
    int s = (t < B) ? bsum[t] : 0;
    lds[t] = s;
    __syncthreads();
    for (int o = 1; o < 1024; o <<= 1) {
        int v = (t >= o) ? lds[t - o] : 0;
        __syncthreads();
        lds[t] += v;
        __syncthreads();
    }
    if (t < B) bsum[t] = lds[t] - s;
}

__global__ void scanC_kernel(int* __restrict__ off, const int* __restrict__ bsum,
                             int N, int E) {
    int i = blockIdx.x * blockDim.x + threadIdx.x;
    if (i < N) off[i] += bsum[i >> 10];
    if (i == 0) off[N] = E;
}

// ---- PassC: per-bucket scatter into col; cur in LDS ----
__global__ __launch_bounds__(256) void scatC_kernel(
    const int* __restrict__ bktCnt, const uint2* __restrict__ bins,
    const int* __restrict__ off, int* __restrict__ col, int N, int cap) {
    __shared__ int cur[BKT_NODES];
    int b = blockIdx.x;
    int lo = b << BKT_SHIFT;
    int n = min(BKT_NODES, N - lo);
    for (int i = threadIdx.x; i < n; i += 256) cur[i] = off[lo + i];
    __syncthreads();
    int cnt = bktCnt[b];
    const uint2* bb = bins + (size_t)b * cap;
    for (int i = threadIdx.x; i < cnt; i += 256) {
        uint2 u = bb[i];
        int pos = atomicAdd(&cur[u.y - lo], 1);
        col[pos] = (int)u.x;
    }
}

// x -> (hi, lo) bf16 split, [n][d] layout preserved
__global__ void split_x_kernel(const float4* __restrict__ in, ushort4* __restrict__ hi,
                               ushort4* __restrict__ lo, int n4) {
    int i = blockIdx.x * blockDim.x + threadIdx.x;
    if (i >= n4) return;
    float4 v = in[i];
    ushort4 h, l;
    h.x = f2b_rne(v.x); l.x = f2b_rne(v.x - b2f(h.x));
    h.y = f2b_rne(v.y); l.y = f2b_rne(v.y - b2f(h.y));
    h.z = f2b_rne(v.z); l.z = f2b_rne(v.z - b2f(h.z));
    h.w = f2b_rne(v.w); l.w = f2b_rne(v.w - b2f(h.w));
    hi[i] = h;
    lo[i] = l;
}

// Build B^T hi/lo for all 3 layers: Bt[n][k], k 0..63 Ws, 64..127 Wn.
__global__ void bprep_kernel(const float* __restrict__ Ws1, const float* __restrict__ Wn1,
                             const float* __restrict__ Ws2, const float* __restrict__ Wn2,
                             const float* __restrict__ Ws3, const float* __restrict__ Wn3,
                             unsigned short* __restrict__ bthi,
                             unsigned short* __restrict__ btlo) {
    int i = blockIdx.x * blockDim.x + threadIdx.x;
    if (i >= 3 * 8192) return;
    int layer = i >> 13;
    int j = i & 8191;
    int n = j >> 7, k = j & 127;
    const float* Ws = layer == 0 ? Ws1 : (layer == 1 ? Ws2 : Ws3);
    const float* Wn = layer == 0 ? Wn1 : (layer == 1 ? Wn2 : Wn3);
    float v = (k < 64) ? Ws[k * 64 + n] : Wn[(k - 64) * 64 + n];
    unsigned short hi = f2b_rne(v);
    bthi[i] = hi;
    btlo[i] = f2b_rne(v - b2f(hi));
}

// wave per node; lane = g*16 + t: edge-group g (0..3), dims t*4..t*4+3.
// Reads bf16-hi rows (128B); end = off[n+1]. Emits mean-scaled agg hi.
__global__ __launch_bounds__(256) void gather64_b16_kernel(
    const unsigned short* __restrict__ hb, const int* __restrict__ off,
    const int* __restrict__ col, const float* __restrict__ dinv,
    unsigned short* __restrict__ ghi, int N) {
    int wave = threadIdx.x >> 6;
    int lane = threadIdx.x & 63;
    int g = lane >> 4;
    int t = lane & 15;
    int n = blockIdx.x * 4 + wave;
    if (n >= N) return;
    int e = off[n], end = off[n + 1];
    float4 a0 = make_float4(0.f, 0.f, 0.f, 0.f);
    float4 a1 = make_float4(0.f, 0.f, 0.f, 0.f);
    float4 a2 = make_float4(0.f, 0.f, 0.f, 0.f);
    float4 a3 = make_float4(0.f, 0.f, 0.f, 0.f);
    for (; e + 16 <= end; e += 16) {
        int s0 = col[e + g];
        int s1 = col[e + 4 + g];
        int s2 = col[e + 8 + g];
        int s3 = col[e + 12 + g];
        ushort4 u0 = *(const ushort4*)&hb[(size_t)s0 * 64 + t * 4];
        ushort4 u1 = *(const ushort4*)&hb[(size_t)s1 * 64 + t * 4];
        ushort4 u2 = *(const ushort4*)&hb[(size_t)s2 * 64 + t * 4];
        ushort4 u3 = *(const ushort4*)&hb[(size_t)s3 * 64 + t * 4];
        a0.x += b2f(u0.x); a0.y += b2f(u0.y); a0.z += b2f(u0.z); a0.w += b2f(u0.w);
        a1.x += b2f(u1.x); a1.y += b2f(u1.y); a1.z += b2f(u1.z); a1.w += b2f(u1.w);
        a2.x += b2f(u2.x); a2.y += b2f(u2.y); a2.z += b2f(u2.z); a2.w += b2f(u2.w);
        a3.x += b2f(u3.x); a3.y += b2f(u3.y); a3.z += b2f(u3.z); a3.w += b2f(u3.w);
    }
    for (; e + 8 <= end; e += 8) {
        int s0 = col[e + g];
        int s1 = col[e + 4 + g];
        ushort4 u0 = *(const ushort4*)&hb[(size_t)s0 * 64 + t * 4];
        ushort4 u1 = *(const ushort4*)&hb[(size_t)s1 * 64 + t * 4];
        a0.x += b2f(u0.x); a0.y += b2f(u0.y); a0.z += b2f(u0.z); a0.w += b2f(u0.w);
        a1.x += b2f(u1.x); a1.y += b2f(u1.y); a1.z += b2f(u1.z); a1.w += b2f(u1.w);
    }
    for (; e < end; e += 4) {
        if (e + g < end) {
            int s0 = col[e + g];
            ushort4 u0 = *(const ushort4*)&hb[(size_t)s0 * 64 + t * 4];
            a2.x += b2f(u0.x); a2.y += b2f(u0.y); a2.z += b2f(u0.z); a2.w += b2f(u0.w);
        }
    }
    float4 acc;
    acc.x = (a0.x + a1.x) + (a2.x + a3.x);
    acc.y = (a0.y + a1.y) + (a2.y + a3.y);
    acc.z = (a0.z + a1.z) + (a2.z + a3.z);
    acc.w = (a0.w + a1.w) + (a2.w + a3.w);
#pragma unroll
    for (int m = 16; m <= 32; m <<= 1) {
        acc.x += __shfl_xor(acc.x, m, 64);
        acc.y += __shfl_xor(acc.y, m, 64);
        acc.z += __shfl_xor(acc.z, m, 64);
        acc.w += __shfl_xor(acc.w, m, 64);
    }
    if (g == 0) {
        float di = dinv[n];
        ushort4 h;
        h.x = f2b_rne(acc.x * di);
        h.y = f2b_rne(acc.y * di);
        h.z = f2b_rne(acc.z * di);
        h.w = f2b_rne(acc.w * di);
        *(ushort4*)&ghi[(size_t)n * 64 + t * 4] = h;
    }
}

// MFMA dense: D = relu([h|agg] @ [Ws;Wn] + b). Hlo nullable (layer 1 only).
// A-frag: m=lane&15, k=quad*8+j. B-frag: n=lane&15 (Bt[n][k]).
// C/D: col=lane&15, row=quad*4+reg. Emits bf16 hi only.
__global__ __launch_bounds__(256) void dense_mfma_kernel(
    const unsigned short* __restrict__ Hhi, const unsigned short* __restrict__ Hlo,
    const unsigned short* __restrict__ Ghi,
    const unsigned short* __restrict__ Bthi, const unsigned short* __restrict__ Btlo,
    const float* __restrict__ b, unsigned short* __restrict__ Dhi, int N) {
    int lane = threadIdx.x & 63;
    int m = lane & 15, quad = lane >> 4;
    int wid = (blockIdx.x * blockDim.x + threadIdx.x) >> 6;
    int nw = (gridDim.x * blockDim.x) >> 6;
    bfrag bhi[4][4];
#pragma unroll
    for (int t = 0; t < 4; ++t)
#pragma unroll
        for (int c = 0; c < 4; ++c)
            bhi[t][c] = *(const bfrag*)(Bthi + (size_t)(t * 16 + m) * 128 + c * 32 + quad * 8);
    float bl[4];
#pragma unroll
    for (int t = 0; t < 4; ++t) bl[t] = b[t * 16 + m];
    int ngroups = (N + 15) >> 4;
    for (int g = wid; g < ngroups; g += nw) {
        int n0 = g << 4;
        int nr = n0 + m;
        if (nr > N - 1) nr = N - 1;
        const unsigned short* hrow = Hhi + (size_t)nr * 64 + quad * 8;
        const unsigned short* grow = Ghi + (size_t)nr * 64 + quad * 8;
        bfrag ah[4], al[2];
        ah[0] = *(const bfrag*)(hrow);
        ah[1] = *(const bfrag*)(hrow + 32);
        ah[2] = *(const bfrag*)(grow);
        ah[3] = *(const bfrag*)(grow + 32);
        if (Hlo) {
            const unsigned short* lrow = Hlo + (size_t)nr * 64 + quad * 8;
            al[0] = *(const bfrag*)(lrow);
            al[1] = *(const bfrag*)(lrow + 32);
        }
#pragma unroll
        for (int t = 0; t < 4; ++t) {
            ffrag acc = {bl[t], bl[t], bl[t], bl[t]};
#pragma unroll
            for (int c = 0; c < 4; ++c) {
                bfrag blo = *(const bfrag*)(Btlo + (size_t)(t * 16 + m) * 128 + c * 32 + quad * 8);
                acc = __builtin_amdgcn_mfma_f32_16x16x32_bf16(ah[c], bhi[t][c], acc, 0, 0, 0);
                if (Hlo && c < 2)
                    acc = __builtin_amdgcn_mfma_f32_16x16x32_bf16(al[c], bhi[t][c], acc, 0, 0, 0);
                acc = __builtin_amdgcn_mfma_f32_16x16x32_bf16(ah[c], blo, acc, 0, 0, 0);
            }
#pragma unroll
            for (int r = 0; r < 4; ++r) {
                int node = n0 + quad * 4 + r;
                if (node < N)
                    Dhi[(size_t)node * 64 + t * 16 + m] = f2b_rne(fmaxf(acc[r], 0.f));
            }
        }
    }
}

// Last dense (layer 3) with fused layer-4 pre-transform: h3 = relu(z3) stays
// in fp32 accs; epilogue computes s = h3·Ws4, g = h3·Wn4 via intra-quad
// shfl_xor reduction (cols live on the 16 lanes m of each quad).
__global__ __launch_bounds__(256) void dense_mfma_last_kernel(
    const unsigned short* __restrict__ Hhi, const unsigned short* __restrict__ Ghi,
    const unsigned short* __restrict__ Bthi, const unsigned short* __restrict__ Btlo,
    const float* __restrict__ b, const float* __restrict__ Ws4,
    const float* __restrict__ Wn4, float* __restrict__ sbuf,
    float* __restrict__ gbuf, int N) {
    int lane = threadIdx.x & 63;
    int m = lane & 15, quad = lane >> 4;
    int wid = (blockIdx.x * blockDim.x + threadIdx.x) >> 6;
    int nw = (gridDim.x * blockDim.x) >> 6;
    bfrag bhi[4][4];
#pragma unroll
    for (int t = 0; t < 4; ++t)
#pragma unroll
        for (int c = 0; c < 4; ++c)
            bhi[t][c] = *(const bfrag*)(Bthi + (size_t)(t * 16 + m) * 128 + c * 32 + quad * 8);
    float bl[4], w4s[4], w4n[4];
#pragma unroll
    for (int t = 0; t < 4; ++t) {
        bl[t] = b[t * 16 + m];
        w4s[t] = Ws4[t * 16 + m];
        w4n[t] = Wn4[t * 16 + m];
    }
    int ngroups = (N + 15) >> 4;
    for (int g = wid; g < ngroups; g += nw) {
        int n0 = g << 4;
        int nr = n0 + m;
        if (nr > N - 1) nr = N - 1;
        const unsigned short* hrow = Hhi + (size_t)nr * 64 + quad * 8;
        const unsigned short* grow = Ghi + (size_t)nr * 64 + quad * 8;
        bfrag ah[4];
        ah[0] = *(const bfrag*)(hrow);
        ah[1] = *(const bfrag*)(hrow + 32);
        ah[2] = *(const bfrag*)(grow);
        ah[3] = *(const bfrag*)(grow + 32);
        ffrag accs[4];
#pragma unroll
        for (int t = 0; t < 4; ++t) {
            ffrag acc = {bl[t], bl[t], bl[t], bl[t]};
#pragma unroll
            for (int c = 0; c < 4; ++c) {
                bfrag blo = *(const bfrag*)(Btlo + (size_t)(t * 16 + m) * 128 + c * 32 + quad * 8);
                acc = __builtin_amdgcn_mfma_f32_16x16x32_bf16(ah[c], bhi[t][c], acc, 0, 0, 0);
                acc = __builtin_amdgcn_mfma_f32_16x16x32_bf16(ah[c], blo, acc, 0, 0, 0);
            }
            accs[t] = acc;
        }
#pragma unroll
        for (int r = 0; r < 4; ++r) {
            float ps = 0.f, pg = 0.f;
#pragma unroll
            for (int t = 0; t < 4; ++t) {
                float v = fmaxf(accs[t][r], 0.f);
                ps = fmaf(v, w4s[t], ps);
                pg = fmaf(v, w4n[t], pg);
            }
#pragma unroll
            for (int mask = 1; mask <= 8; mask <<= 1) {
                ps += __shfl_xor(ps, mask, 64);
                pg += __shfl_xor(pg, mask, 64);
            }
            int node = n0 + quad * 4 + r;
            if (m == 0 && node < N) {
                sbuf[node] = ps;
                gbuf[node] = pg;
            }
        }
    }
}

// thread per node: scalar CSR gather of g (400 KB, L2-resident) + sigmoid
__global__ void final_kernel(const float* __restrict__ s, const float* __restrict__ dinv,
                             const float* __restrict__ g, const int* __restrict__ off,
                             const int* __restrict__ col,
                             const float* __restrict__ b4, float* __restrict__ out, int N) {
    int n = blockIdx.x * blockDim.x + threadIdx.x;
    if (n >= N) return;
    float a = 0.f;
    int e = off[n], end = off[n + 1];
    for (; e < end; ++e) a += g[col[e]];
    float z = s[n] + dinv[n] * a + b4[0];
    out[n] = 1.0f / (1.0f + expf(-z));
}

static inline int cdiv(long long a, long long b) { return (int)((a + b - 1) / b); }

extern "C" void kernel_launch(void* const* d_in, const int* in_sizes, int n_in,
                              void* d_out, int out_size, void* d_ws, size_t ws_size,
                              hipStream_t stream) {
    const float* x   = (const float*)d_in[0];
    const int*   ei  = (const int*)d_in[1];
    const float* Ws1 = (const float*)d_in[2];
    const float* Wn1 = (const float*)d_in[3];
    const float* b1  = (const float*)d_in[4];
    const float* Ws2 = (const float*)d_in[5];
    const float* Wn2 = (const float*)d_in[6];
    const float* b2  = (const float*)d_in[7];
    const float* Ws3 = (const float*)d_in[8];
    const float* Wn3 = (const float*)d_in[9];
    const float* b3  = (const float*)d_in[10];
    const float* Ws4 = (const float*)d_in[11];
    const float* Wn4 = (const float*)d_in[12];
    const float* b4  = (const float*)d_in[13];
    float* out = (float*)d_out;

    const int N = in_sizes[0] / 64;
    const int E = in_sizes[1] / 2;

    const int nbkt = cdiv(N, BKT_NODES);                 // <=256
    const int cap  = E / nbkt + E / nbkt / 8 + 64;       // ~12.5% margin

    // workspace layout (bins first: 8B alignment)
    uint2* bins = (uint2*)d_ws;                          // nbkt*cap
    unsigned short* HhiA = (unsigned short*)(bins + (size_t)nbkt * cap);
    unsigned short* HloA = HhiA + (size_t)N * 64;        // x lo only
    unsigned short* HhiB = HloA + (size_t)N * 64;
    unsigned short* Ghi  = HhiB + (size_t)N * 64;
    unsigned short* Bth  = Ghi + (size_t)N * 64;         // 3*8192
    unsigned short* Btl  = Bth + 3 * 8192;               // 3*8192
    float* dinv = (float*)(Btl + 3 * 8192);              // N
    float* sbuf = dinv + N;                              // N
    float* gbuf = sbuf + N;                              // N
    int*   degi = (int*)(gbuf + N);                      // N
    int*   off  = degi + N;                              // N+1
    int*   col  = off + N + 1;                           // E
    int*   bsum = col + E;                               // 1024
    int*   bktc = bsum + 1024;                           // 256
    int*   flag = bktc + 256;                            // 1

    const int BT = 256;
    const int gridN  = cdiv(N, BT);
    const int gridNd = cdiv(N, 4);
    const int gridMM = cdiv(cdiv(N, 16), 4);
    const int B      = cdiv(N, 1024);
    const int binBlocks = 512;
    const int chunksz = cdiv(E, binBlocks);

    // ---- CSR build: counting sort (bin -> degree -> scan -> scatter) ----
    init_kernel<<<1, BT, 0, stream>>>(ei, bktc, flag);
    binA_kernel<<<binBlocks, BT, 0, stream>>>(ei, flag, bktc, bins, E, nbkt, cap, chunksz);
    degB_kernel<<<nbkt, BT, 0, stream>>>(bktc, bins, degi, dinv, N, cap);
    scanA_kernel<<<B, 256, 0, stream>>>(degi, off, bsum, N);
    scanB_kernel<<<1, 1024, 0, stream>>>(bsum, B);
    scanC_kernel<<<gridN, BT, 0, stream>>>(off, bsum, N, E);
    scatC_kernel<<<nbkt, BT, 0, stream>>>(bktc, bins, off, col, N, cap);

    // ---- weight prep (B^T hi/lo, all 3 layers) + x split ----
    bprep_kernel<<<96, BT, 0, stream>>>(Ws1, Wn1, Ws2, Wn2, Ws3, Wn3, Bth, Btl);
    split_x_kernel<<<cdiv((long long)N * 16, BT), BT, 0, stream>>>(
        (const float4*)x, (ushort4*)HhiA, (ushort4*)HloA, N * 16);

    // ---- layer 1: x (hi/lo) -> HhiB ----
    gather64_b16_kernel<<<gridNd, BT, 0, stream>>>(HhiA, off, col, dinv, Ghi, N);
    dense_mfma_kernel<<<gridMM, BT, 0, stream>>>(HhiA, HloA, Ghi, Bth, Btl, b1, HhiB, N);

    // ---- layer 2: HhiB -> HhiA (hi-only) ----
    gather64_b16_kernel<<<gridNd, BT, 0, stream>>>(HhiB, off, col, dinv, Ghi, N);
    dense_mfma_kernel<<<gridMM, BT, 0, stream>>>(HhiB, (const unsigned short*)nullptr,
                                                 Ghi, Bth + 8192, Btl + 8192, b2, HhiA, N);

    // ---- layer 3 + fused layer-4 pre-transform: HhiA -> sbuf,gbuf ----
    gather64_b16_kernel<<<gridNd, BT, 0, stream>>>(HhiA, off, col, dinv, Ghi, N);
    dense_mfma_last_kernel<<<gridMM, BT, 0, stream>>>(HhiA, Ghi, Bth + 16384,
                                                      Btl + 16384, b3, Ws4, Wn4,
                                                      sbuf, gbuf, N);

    // ---- layer 4 (64->1): scalar CSR gather + sigmoid ----
    final_kernel<<<gridN, BT, 0, stream>>>(sbuf, dinv, gbuf, off, col, b4, out, N);
}

// Round 11
// 417.284 us; speedup vs baseline: 1.5413x; 1.0233x over previous
//
#include <hip/hip_runtime.h>
#include <hip/hip_bf16.h>
#include <math.h>

// ---------------------------------------------------------------------------
// ActorGNN: 4-layer GraphConv. R11:
//  - gather+dense fused per layer (wave gathers 16 nodes' agg into LDS bf16,
//    then MFMAs them; no Ghi round-trip, no block barrier - wave-local LDS).
//    B-frags loaded after gather phase -> low VGPR during latency-bound part.
//  - CSR build: binA packs (dstLocal<<23|src) into one uint; bucketCSR does
//    degree+local-scan+scatter+dinv in ONE kernel using bucket-local col
//    regions (off/offe arrays, no global scan). 7 kernels -> 2.
//  - all H state hi-only bf16 (absmax pinned at 3.9e-3 by gather path across
//    R7-R10 precision reductions); weights keep hi/lo split.
//  - 8 dispatches total (was 16): ~110us of gaps/serialization attacked.
// ---------------------------------------------------------------------------

using bfrag = __attribute__((ext_vector_type(8))) short;   // 8 bf16 (4 VGPR)
using ffrag = __attribute__((ext_vector_type(4))) float;   // 4 fp32 acc

#define BKT_SHIFT 9                 // 512 nodes per bucket
#define BKT_NODES (1 << BKT_SHIFT)

__device__ __forceinline__ int load_idx32(const int* __restrict__ ei32, int is64,
                                          long long pos) {
    return is64 ? ei32[2 * pos] : ei32[pos];
}

__device__ __forceinline__ unsigned short f2b_rne(float f) {
    union { float f; unsigned u; } c;
    c.f = f;
    unsigned r = c.u + 0x7FFFu + ((c.u >> 16) & 1u);
    return (unsigned short)(r >> 16);
}

__device__ __forceinline__ float b2f(unsigned short u) {
    union { unsigned u; float f; } c;
    c.u = ((unsigned)u) << 16;
    return c.f;
}

// ---- weight prep (B^T hi/lo, 3 layers) + bktc zero + int64 detect ----
__global__ void bprep_init_kernel(
    const float* __restrict__ Ws1, const float* __restrict__ Wn1,
    const float* __restrict__ Ws2, const float* __restrict__ Wn2,
    const float* __restrict__ Ws3, const float* __restrict__ Wn3,
    unsigned short* __restrict__ bthi, unsigned short* __restrict__ btlo,
    const int* __restrict__ ei, int* __restrict__ bktc, int* __restrict__ flag) {
    if (blockIdx.x == 0) {
        bktc[threadIdx.x] = 0;
        if (threadIdx.x == 0) {
            int allz = 1;
            for (int i = 0; i < 32; ++i)
                if (ei[2 * i + 1] != 0) allz = 0;
            *flag = allz;
        }
    }
    int i = blockIdx.x * 256 + threadIdx.x;
    if (i >= 3 * 8192) return;
    int layer = i >> 13;
    int j = i & 8191;
    int n = j >> 7, k = j & 127;
    const float* Ws = layer == 0 ? Ws1 : (layer == 1 ? Ws2 : Ws3);
    const float* Wn = layer == 0 ? Wn1 : (layer == 1 ? Wn2 : Wn3);
    float v = (k < 64) ? Ws[k * 64 + n] : Wn[(k - 64) * 64 + n];
    unsigned short hi = f2b_rne(v);
    bthi[i] = hi;
    btlo[i] = f2b_rne(v - b2f(hi));
}

// x -> bf16 hi, [n][d] layout preserved
__global__ void split_x_kernel(const float4* __restrict__ in, ushort4* __restrict__ hi,
                               int n4) {
    int i = blockIdx.x * blockDim.x + threadIdx.x;
    if (i >= n4) return;
    float4 v = in[i];
    ushort4 h;
    h.x = f2b_rne(v.x); h.y = f2b_rne(v.y); h.z = f2b_rne(v.z); h.w = f2b_rne(v.w);
    hi[i] = h;
}

// ---- PassA: bin edges into dst-buckets, packed (dstLocal<<23 | src) ----
__global__ __launch_bounds__(256) void binA_kernel(
    const int* __restrict__ ei32, const int* __restrict__ flagp,
    int* __restrict__ bktCnt, unsigned* __restrict__ bins, int E, int nbkt,
    int cap, int chunksz) {
    __shared__ int cnt[256];
    __shared__ int base[256];
    int is64 = *flagp;
    int elo = blockIdx.x * chunksz;
    int ehi = min(E, elo + chunksz);
    if (elo >= E) return;
    for (int i = threadIdx.x; i < nbkt; i += 256) cnt[i] = 0;
    __syncthreads();
    for (int e = elo + (int)threadIdx.x; e < ehi; e += 256) {
        int dst = load_idx32(ei32, is64, (long long)E + e);
        atomicAdd(&cnt[dst >> BKT_SHIFT], 1);
    }
    __syncthreads();
    for (int i = threadIdx.x; i < nbkt; i += 256) {
        base[i] = atomicAdd(&bktCnt[i], cnt[i]);
        cnt[i] = 0;
    }
    __syncthreads();
    for (int e = elo + (int)threadIdx.x; e < ehi; e += 256) {
        int dst = load_idx32(ei32, is64, (long long)E + e);
        int src = load_idx32(ei32, is64, e);
        int b = dst >> BKT_SHIFT;
        int r = atomicAdd(&cnt[b], 1);
        bins[(size_t)b * cap + base[b] + r] =
            ((unsigned)(dst & (BKT_NODES - 1)) << 23) | (unsigned)src;
    }
}

// ---- bucketCSR: degree + local scan + scatter + dinv, one kernel ----
// col is bucket-local: node n in bucket b has edges at [off[n], offe[n])
// inside region [b*cap, b*cap+cnt).
__global__ __launch_bounds__(256) void bucketCSR_kernel(
    const int* __restrict__ bktCnt, const unsigned* __restrict__ bins,
    int* __restrict__ off, int* __restrict__ offe, int* __restrict__ col,
    float* __restrict__ dinv, int N, int cap) {
    __shared__ int deg[BKT_NODES];
    __shared__ int loc[BKT_NODES];
    __shared__ int ssum[256];
    int b = blockIdx.x;
    int lo = b << BKT_SHIFT;
    int n = min(BKT_NODES, N - lo);
    for (int i = threadIdx.x; i < BKT_NODES; i += 256) deg[i] = 0;
    __syncthreads();
    int cnt = bktCnt[b];
    const unsigned* bb = bins + (size_t)b * cap;
    for (int i = threadIdx.x; i < cnt; i += 256)
        atomicAdd(&deg[bb[i] >> 23], 1);
    __syncthreads();
    int t = threadIdx.x;
    int d0 = deg[2 * t], d1 = deg[2 * t + 1];
    int s = d0 + d1;
    ssum[t] = s;
    __syncthreads();
    for (int o = 1; o < 256; o <<= 1) {
        int v = (t >= o) ? ssum[t - o] : 0;
        __syncthreads();
        ssum[t] += v;
        __syncthreads();
    }
    int excl = ssum[t] - s;
    loc[2 * t] = excl;
    loc[2 * t + 1] = excl + d0;
    __syncthreads();
    int base = b * cap;
    for (int i = threadIdx.x; i < n; i += 256) {
        int d = deg[i];
        off[lo + i] = base + loc[i];
        offe[lo + i] = base + loc[i] + d;
        dinv[lo + i] = 1.0f / fmaxf((float)d, 1.0f);
    }
    __syncthreads();
    for (int i = threadIdx.x; i < cnt; i += 256) {
        unsigned p = bb[i];
        int pos = atomicAdd(&loc[p >> 23], 1);
        col[base + pos] = (int)(p & 0x7FFFFFu);
    }
}

// ---- fused gather + MFMA dense layer ----
// Block = 4 waves x 16 nodes. Per wave: gather agg for its 16 nodes into LDS
// (bf16, stride 72 shorts), then D = relu([h|agg] @ [Ws;Wn] + b) via MFMA.
// Wave-local LDS -> no barrier. A-frag: m=lane&15, k=quad*8+j.
// C/D: col=lane&15, row=quad*4+reg.
#define AGG_STRIDE 72
__global__ __launch_bounds__(256) void layer_fused_kernel(
    const unsigned short* __restrict__ Hhi, const int* __restrict__ off,
    const int* __restrict__ offe, const int* __restrict__ col,
    const float* __restrict__ dinv,
    const unsigned short* __restrict__ Bthi, const unsigned short* __restrict__ Btlo,
    const float* __restrict__ b, unsigned short* __restrict__ Dhi, int N) {
    __shared__ unsigned short aggL[4 * 16 * AGG_STRIDE];
    int wave = threadIdx.x >> 6;
    int lane = threadIdx.x & 63;
    int g = lane >> 4;
    int t16 = lane & 15;
    int n0 = blockIdx.x * 64 + wave * 16;
    unsigned short* myAgg = aggL + wave * 16 * AGG_STRIDE;
    // ---- gather phase (16 nodes sequential; 16 edges in flight) ----
    for (int i = 0; i < 16; ++i) {
        int n = n0 + i;
        if (n >= N) {
            if (g == 0) {
                ushort4 z = {0, 0, 0, 0};
                *(ushort4*)&myAgg[i * AGG_STRIDE + t16 * 4] = z;
            }
            continue;
        }
        int e = off[n], end = offe[n];
        float4 a0 = make_float4(0.f, 0.f, 0.f, 0.f);
        float4 a1 = make_float4(0.f, 0.f, 0.f, 0.f);
        float4 a2 = make_float4(0.f, 0.f, 0.f, 0.f);
        float4 a3 = make_float4(0.f, 0.f, 0.f, 0.f);
        for (; e + 16 <= end; e += 16) {
            int s0 = col[e + g];
            int s1 = col[e + 4 + g];
            int s2 = col[e + 8 + g];
            int s3 = col[e + 12 + g];
            ushort4 u0 = *(const ushort4*)&Hhi[(size_t)s0 * 64 + t16 * 4];
            ushort4 u1 = *(const ushort4*)&Hhi[(size_t)s1 * 64 + t16 * 4];
            ushort4 u2 = *(const ushort4*)&Hhi[(size_t)s2 * 64 + t16 * 4];
            ushort4 u3 = *(const ushort4*)&Hhi[(size_t)s3 * 64 + t16 * 4];
            a0.x += b2f(u0.x); a0.y += b2f(u0.y); a0.z += b2f(u0.z); a0.w += b2f(u0.w);
            a1.x += b2f(u1.x); a1.y += b2f(u1.y); a1.z += b2f(u1.z); a1.w += b2f(u1.w);
            a2.x += b2f(u2.x); a2.y += b2f(u2.y); a2.z += b2f(u2.z); a2.w += b2f(u2.w);
            a3.x += b2f(u3.x); a3.y += b2f(u3.y); a3.z += b2f(u3.z); a3.w += b2f(u3.w);
        }
        for (; e + 8 <= end; e += 8) {
            int s0 = col[e + g];
            int s1 = col[e + 4 + g];
            ushort4 u0 = *(const ushort4*)&Hhi[(size_t)s0 * 64 + t16 * 4];
            ushort4 u1 = *(const ushort4*)&Hhi[(size_t)s1 * 64 + t16 * 4];
            a0.x += b2f(u0.x); a0.y += b2f(u0.y); a0.z += b2f(u0.z); a0.w += b2f(u0.w);
            a1.x += b2f(u1.x); a1.y += b2f(u1.y); a1.z += b2f(u1.z); a1.w += b2f(u1.w);
        }
        for (; e < end; e += 4) {
            if (e + g < end) {
                int s0 = col[e + g];
                ushort4 u0 = *(const ushort4*)&Hhi[(size_t)s0 * 64 + t16 * 4];
                a2.x += b2f(u0.x); a2.y += b2f(u0.y); a2.z += b2f(u0.z); a2.w += b2f(u0.w);
            }
        }
        float4 acc;
        acc.x = (a0.x + a1.x) + (a2.x + a3.x);
        acc.y = (a0.y + a1.y) + (a2.y + a3.y);
        acc.z = (a0.z + a1.z) + (a2.z + a3.z);
        acc.w = (a0.w + a1.w) + (a2.w + a3.w);
#pragma unroll
        for (int msk = 16; msk <= 32; msk <<= 1) {
            acc.x += __shfl_xor(acc.x, msk, 64);
            acc.y += __shfl_xor(acc.y, msk, 64);
            acc.z += __shfl_xor(acc.z, msk, 64);
            acc.w += __shfl_xor(acc.w, msk, 64);
        }
        if (g == 0) {
            float di = dinv[n];
            ushort4 h;
            h.x = f2b_rne(acc.x * di);
            h.y = f2b_rne(acc.y * di);
            h.z = f2b_rne(acc.z * di);
            h.w = f2b_rne(acc.w * di);
            *(ushort4*)&myAgg[i * AGG_STRIDE + t16 * 4] = h;
        }
    }
    // ---- dense phase (wave-local; LDS deps handled by waitcnt) ----
    int m = t16, quad = g;
    int nr = n0 + m;
    if (nr > N - 1) nr = N - 1;
    const unsigned short* hrow = Hhi + (size_t)nr * 64 + quad * 8;
    bfrag ah[4];
    ah[0] = *(const bfrag*)(hrow);
    ah[1] = *(const bfrag*)(hrow + 32);
    ah[2] = *(const bfrag*)&myAgg[m * AGG_STRIDE + quad * 8];
    ah[3] = *(const bfrag*)&myAgg[m * AGG_STRIDE + 32 + quad * 8];
#pragma unroll
    for (int t = 0; t < 4; ++t) {
        float bl = b[t * 16 + m];
        ffrag acc = {bl, bl, bl, bl};
#pragma unroll
        for (int c = 0; c < 4; ++c) {
            bfrag bh = *(const bfrag*)(Bthi + (size_t)(t * 16 + m) * 128 + c * 32 + quad * 8);
            bfrag bw = *(const bfrag*)(Btlo + (size_t)(t * 16 + m) * 128 + c * 32 + quad * 8);
            acc = __builtin_amdgcn_mfma_f32_16x16x32_bf16(ah[c], bh, acc, 0, 0, 0);
            acc = __builtin_amdgcn_mfma_f32_16x16x32_bf16(ah[c], bw, acc, 0, 0, 0);
        }
#pragma unroll
        for (int r = 0; r < 4; ++r) {
            int node = n0 + quad * 4 + r;
            if (node < N)
                Dhi[(size_t)node * 64 + t * 16 + m] = f2b_rne(fmaxf(acc[r], 0.f));
        }
    }
}

// ---- fused layer 3 + layer-4 pre-transform (s,g from fp32 accs) ----
__global__ __launch_bounds__(256) void layer_fused_last_kernel(
    const unsigned short* __restrict__ Hhi, const int* __restrict__ off,
    const int* __restrict__ offe, const int* __restrict__ col,
    const float* __restrict__ dinv,
    const unsigned short* __restrict__ Bthi, const unsigned short* __restrict__ Btlo,
    const float* __restrict__ b, const float* __restrict__ Ws4,
    const float* __restrict__ Wn4, float* __restrict__ sbuf,
    float* __restrict__ gbuf, int N) {
    __shared__ unsigned short aggL[4 * 16 * AGG_STRIDE];
    int wave = threadIdx.x >> 6;
    int lane = threadIdx.x & 63;
    int g = lane >> 4;
    int t16 = lane & 15;
    int n0 = blockIdx.x * 64 + wave * 16;
    unsigned short* myAgg = aggL + wave * 16 * AGG_STRIDE;
    for (int i = 0; i < 16; ++i) {
        int n = n0 + i;
        if (n >= N) {
            if (g == 0) {
                ushort4 z = {0, 0, 0, 0};
                *(ushort4*)&myAgg[i * AGG_STRIDE + t16 * 4] = z;
            }
            continue;
        }
        int e = off[n], end = offe[n];
        float4 a0 = make_float4(0.f, 0.f, 0.f, 0.f);
        float4 a1 = make_float4(0.f, 0.f, 0.f, 0.f);
        float4 a2 = make_float4(0.f, 0.f, 0.f, 0.f);
        float4 a3 = make_float4(0.f, 0.f, 0.f, 0.f);
        for (; e + 16 <= end; e += 16) {
            int s0 = col[e + g];
            int s1 = col[e + 4 + g];
            int s2 = col[e + 8 + g];
            int s3 = col[e + 12 + g];
            ushort4 u0 = *(const ushort4*)&Hhi[(size_t)s0 * 64 + t16 * 4];
            ushort4 u1 = *(const ushort4*)&Hhi[(size_t)s1 * 64 + t16 * 4];
            ushort4 u2 = *(const ushort4*)&Hhi[(size_t)s2 * 64 + t16 * 4];
            ushort4 u3 = *(const ushort4*)&Hhi[(size_t)s3 * 64 + t16 * 4];
            a0.x += b2f(u0.x); a0.y += b2f(u0.y); a0.z += b2f(u0.z); a0.w += b2f(u0.w);
            a1.x += b2f(u1.x); a1.y += b2f(u1.y); a1.z += b2f(u1.z); a1.w += b2f(u1.w);
            a2.x += b2f(u2.x); a2.y += b2f(u2.y); a2.z += b2f(u2.z); a2.w += b2f(u2.w);
            a3.x += b2f(u3.x); a3.y += b2f(u3.y); a3.z += b2f(u3.z); a3.w += b2f(u3.w);
        }
        for (; e + 8 <= end; e += 8) {
            int s0 = col[e + g];
            int s1 = col[e + 4 + g];
            ushort4 u0 = *(const ushort4*)&Hhi[(size_t)s0 * 64 + t16 * 4];
            ushort4 u1 = *(const ushort4*)&Hhi[(size_t)s1 * 64 + t16 * 4];
            a0.x += b2f(u0.x); a0.y += b2f(u0.y); a0.z += b2f(u0.z); a0.w += b2f(u0.w);
            a1.x += b2f(u1.x); a1.y += b2f(u1.y); a1.z += b2f(u1.z); a1.w += b2f(u1.w);
        }
        for (; e < end; e += 4) {
            if (e + g < end) {
                int s0 = col[e + g];
                ushort4 u0 = *(const ushort4*)&Hhi[(size_t)s0 * 64 + t16 * 4];
                a2.x += b2f(u0.x); a2.y += b2f(u0.y); a2.z += b2f(u0.z); a2.w += b2f(u0.w);
            }
        }
        float4 acc;
        acc.x = (a0.x + a1.x) + (a2.x + a3.x);
        acc.y = (a0.y + a1.y) + (a2.y + a3.y);
        acc.z = (a0.z + a1.z) + (a2.z + a3.z);
        acc.w = (a0.w + a1.w) + (a2.w + a3.w);
#pragma unroll
        for (int msk = 16; msk <= 32; msk <<= 1) {
            acc.x += __shfl_xor(acc.x, msk, 64);
            acc.y += __shfl_xor(acc.y, msk, 64);
            acc.z += __shfl_xor(acc.z, msk, 64);
            acc.w += __shfl_xor(acc.w, msk, 64);
        }
        if (g == 0) {
            float di = dinv[n];
            ushort4 h;
            h.x = f2b_rne(acc.x * di);
            h.y = f2b_rne(acc.y * di);
            h.z = f2b_rne(acc.z * di);
            h.w = f2b_rne(acc.w * di);
            *(ushort4*)&myAgg[i * AGG_STRIDE + t16 * 4] = h;
        }
    }
    int m = t16, quad = g;
    int nr = n0 + m;
    if (nr > N - 1) nr = N - 1;
    const unsigned short* hrow = Hhi + (size_t)nr * 64 + quad * 8;
    bfrag ah[4];
    ah[0] = *(const bfrag*)(hrow);
    ah[1] = *(const bfrag*)(hrow + 32);
    ah[2] = *(const bfrag*)&myAgg[m * AGG_STRIDE + quad * 8];
    ah[3] = *(const bfrag*)&myAgg[m * AGG_STRIDE + 32 + quad * 8];
    ffrag accs[4];
#pragma unroll
    for (int t = 0; t < 4; ++t) {
        float bl = b[t * 16 + m];
        ffrag acc = {bl, bl, bl, bl};
#pragma unroll
        for (int c = 0; c < 4; ++c) {
            bfrag bh = *(const bfrag*)(Bthi + (size_t)(t * 16 + m) * 128 + c * 32 + quad * 8);
            bfrag bw = *(const bfrag*)(Btlo + (size_t)(t * 16 + m) * 128 + c * 32 + quad * 8);
            acc = __builtin_amdgcn_mfma_f32_16x16x32_bf16(ah[c], bh, acc, 0, 0, 0);
            acc = __builtin_amdgcn_mfma_f32_16x16x32_bf16(ah[c], bw, acc, 0, 0, 0);
        }
        accs[t] = acc;
    }
    float w4s[4], w4n[4];
#pragma unroll
    for (int t = 0; t < 4; ++t) {
        w4s[t] = Ws4[t * 16 + m];
        w4n[t] = Wn4[t * 16 + m];
    }
#pragma unroll
    for (int r = 0; r < 4; ++r) {
        float ps = 0.f, pg = 0.f;
#pragma unroll
        for (int t = 0; t < 4; ++t) {
            float v = fmaxf(accs[t][r], 0.f);
            ps = fmaf(v, w4s[t], ps);
            pg = fmaf(v, w4n[t], pg);
        }
#pragma unroll
        for (int mask = 1; mask <= 8; mask <<= 1) {
            ps += __shfl_xor(ps, mask, 64);
            pg += __shfl_xor(pg, mask, 64);
        }
        int node = n0 + quad * 4 + r;
        if (m == 0 && node < N) {
            sbuf[node] = ps;
            gbuf[node] = pg;
        }
    }
}

// thread per node: scalar CSR gather of g (400 KB, L2-resident) + sigmoid
__global__ void final_kernel(const float* __restrict__ s, const float* __restrict__ dinv,
                             const float* __restrict__ g, const int* __restrict__ off,
                             const int* __restrict__ offe, const int* __restrict__ col,
                             const float* __restrict__ b4, float* __restrict__ out, int N) {
    int n = blockIdx.x * blockDim.x + threadIdx.x;
    if (n >= N) return;
    float a = 0.f;
    int e = off[n], end = offe[n];
    for (; e < end; ++e) a += g[col[e]];
    float z = s[n] + dinv[n] * a + b4[0];
    out[n] = 1.0f / (1.0f + expf(-z));
}

static inline int cdiv(long long a, long long b) { return (int)((a + b - 1) / b); }

extern "C" void kernel_launch(void* const* d_in, const int* in_sizes, int n_in,
                              void* d_out, int out_size, void* d_ws, size_t ws_size,
                              hipStream_t stream) {
    const float* x   = (const float*)d_in[0];
    const int*   ei  = (const int*)d_in[1];
    const float* Ws1 = (const float*)d_in[2];
    const float* Wn1 = (const float*)d_in[3];
    const float* b1  = (const float*)d_in[4];
    const float* Ws2 = (const float*)d_in[5];
    const float* Wn2 = (const float*)d_in[6];
    const float* b2  = (const float*)d_in[7];
    const float* Ws3 = (const float*)d_in[8];
    const float* Wn3 = (const float*)d_in[9];
    const float* b3  = (const float*)d_in[10];
    const float* Ws4 = (const float*)d_in[11];
    const float* Wn4 = (const float*)d_in[12];
    const float* b4  = (const float*)d_in[13];
    float* out = (float*)d_out;

    const int N = in_sizes[0] / 64;
    const int E = in_sizes[1] / 2;

    const int nbkt = cdiv(N, BKT_NODES);                 // <=256
    const int cap  = E / nbkt + E / nbkt / 8 + 64;       // ~12.5% margin

    // workspace layout
    unsigned* bins = (unsigned*)d_ws;                    // nbkt*cap
    int* col = (int*)(bins + (size_t)nbkt * cap);        // nbkt*cap (bucket-local)
    unsigned short* HhiA = (unsigned short*)(col + (size_t)nbkt * cap);  // N*64
    unsigned short* HhiB = HhiA + (size_t)N * 64;        // N*64
    unsigned short* Bth  = HhiB + (size_t)N * 64;        // 3*8192
    unsigned short* Btl  = Bth + 3 * 8192;               // 3*8192
    float* dinv = (float*)(Btl + 3 * 8192);              // N
    float* sbuf = dinv + N;                              // N
    float* gbuf = sbuf + N;                              // N
    int*   off  = (int*)(gbuf + N);                      // N
    int*   offe = off + N;                               // N
    int*   bktc = offe + N;                              // 256
    int*   flag = bktc + 256;                            // 1

    const int BT = 256;
    const int gridN  = cdiv(N, BT);
    const int gridL  = cdiv(N, 64);                      // fused layer blocks
    const int binBlocks = 512;
    const int chunksz = cdiv(E, binBlocks);

    // ---- prep: weights + init (96 blocks), x->bf16 ----
    bprep_init_kernel<<<96, BT, 0, stream>>>(Ws1, Wn1, Ws2, Wn2, Ws3, Wn3,
                                             Bth, Btl, ei, bktc, flag);
    split_x_kernel<<<cdiv((long long)N * 16, BT), BT, 0, stream>>>(
        (const float4*)x, (ushort4*)HhiA, N * 16);

    // ---- CSR build: 2 kernels ----
    binA_kernel<<<binBlocks, BT, 0, stream>>>(ei, flag, bktc, bins, E, nbkt, cap, chunksz);
    bucketCSR_kernel<<<nbkt, BT, 0, stream>>>(bktc, bins, off, offe, col, dinv, N, cap);

    // ---- layers 1-3 (fused gather+dense) ----
    layer_fused_kernel<<<gridL, BT, 0, stream>>>(HhiA, off, offe, col, dinv,
                                                 Bth, Btl, b1, HhiB, N);
    layer_fused_kernel<<<gridL, BT, 0, stream>>>(HhiB, off, offe, col, dinv,
                                                 Bth + 8192, Btl + 8192, b2, HhiA, N);
    layer_fused_last_kernel<<<gridL, BT, 0, stream>>>(HhiA, off, offe, col, dinv,
                                                      Bth + 16384, Btl + 16384, b3,
                                                      Ws4, Wn4, sbuf, gbuf, N);

    // ---- layer 4 (64->1): scalar CSR gather + sigmoid ----
    final_kernel<<<gridN, BT, 0, stream>>>(sbuf, dinv, gbuf, off, offe, col, b4, out, N);
}

// Round 12
// 404.649 us; speedup vs baseline: 1.5894x; 1.0312x over previous
//
#include <hip/hip_runtime.h>
#include <hip/hip_bf16.h>
#include <math.h>

// ---------------------------------------------------------------------------
// ActorGNN: 4-layer GraphConv. R12 (fused v2):
//  - R11's fused layer starved MLP: 16 nodes/wave serial -> only 6250 waves,
//    occupancy 34%, hbm 1.4 TB/s (vs 3.2 standalone). v2: block = 4 waves
//    handles 16 nodes (4 nodes/wave serial), grid 4x -> 32 waves/CU; dense
//    phase splits output dims across the 4 waves (wave w = cols w*16..+15).
//    One __syncthreads between phases.
//  - CSR 2-kernel build, hi-only bf16 H, split-weight MFMA: as R11.
// ---------------------------------------------------------------------------

using bfrag = __attribute__((ext_vector_type(8))) short;   // 8 bf16 (4 VGPR)
using ffrag = __attribute__((ext_vector_type(4))) float;   // 4 fp32 acc

#define BKT_SHIFT 9                 // 512 nodes per bucket
#define BKT_NODES (1 << BKT_SHIFT)
#define AGG_STRIDE 72               // shorts; 144B row pitch in LDS

__device__ __forceinline__ int load_idx32(const int* __restrict__ ei32, int is64,
                                          long long pos) {
    return is64 ? ei32[2 * pos] : ei32[pos];
}

__device__ __forceinline__ unsigned short f2b_rne(float f) {
    union { float f; unsigned u; } c;
    c.f = f;
    unsigned r = c.u + 0x7FFFu + ((c.u >> 16) & 1u);
    return (unsigned short)(r >> 16);
}

__device__ __forceinline__ float b2f(unsigned short u) {
    union { unsigned u; float f; } c;
    c.u = ((unsigned)u) << 16;
    return c.f;
}

// ---- weight prep (B^T hi/lo, 3 layers) + bktc zero + int64 detect ----
__global__ void bprep_init_kernel(
    const float* __restrict__ Ws1, const float* __restrict__ Wn1,
    const float* __restrict__ Ws2, const float* __restrict__ Wn2,
    const float* __restrict__ Ws3, const float* __restrict__ Wn3,
    unsigned short* __restrict__ bthi, unsigned short* __restrict__ btlo,
    const int* __restrict__ ei, int* __restrict__ bktc, int* __restrict__ flag) {
    if (blockIdx.x == 0) {
        bktc[threadIdx.x] = 0;
        if (threadIdx.x == 0) {
            int allz = 1;
            for (int i = 0; i < 32; ++i)
                if (ei[2 * i + 1] != 0) allz = 0;
            *flag = allz;
        }
    }
    int i = blockIdx.x * 256 + threadIdx.x;
    if (i >= 3 * 8192) return;
    int layer = i >> 13;
    int j = i & 8191;
    int n = j >> 7, k = j & 127;
    const float* Ws = layer == 0 ? Ws1 : (layer == 1 ? Ws2 : Ws3);
    const float* Wn = layer == 0 ? Wn1 : (layer == 1 ? Wn2 : Wn3);
    float v = (k < 64) ? Ws[k * 64 + n] : Wn[(k - 64) * 64 + n];
    unsigned short hi = f2b_rne(v);
    bthi[i] = hi;
    btlo[i] = f2b_rne(v - b2f(hi));
}

// x -> bf16 hi, [n][d] layout preserved
__global__ void split_x_kernel(const float4* __restrict__ in, ushort4* __restrict__ hi,
                               int n4) {
    int i = blockIdx.x * blockDim.x + threadIdx.x;
    if (i >= n4) return;
    float4 v = in[i];
    ushort4 h;
    h.x = f2b_rne(v.x); h.y = f2b_rne(v.y); h.z = f2b_rne(v.z); h.w = f2b_rne(v.w);
    hi[i] = h;
}

// ---- PassA: bin edges into dst-buckets, packed (dstLocal<<23 | src) ----
__global__ __launch_bounds__(256) void binA_kernel(
    const int* __restrict__ ei32, const int* __restrict__ flagp,
    int* __restrict__ bktCnt, unsigned* __restrict__ bins, int E, int nbkt,
    int cap, int chunksz) {
    __shared__ int cnt[256];
    __shared__ int base[256];
    int is64 = *flagp;
    int elo = blockIdx.x * chunksz;
    int ehi = min(E, elo + chunksz);
    if (elo >= E) return;
    for (int i = threadIdx.x; i < nbkt; i += 256) cnt[i] = 0;
    __syncthreads();
    for (int e = elo + (int)threadIdx.x; e < ehi; e += 256) {
        int dst = load_idx32(ei32, is64, (long long)E + e);
        atomicAdd(&cnt[dst >> BKT_SHIFT], 1);
    }
    __syncthreads();
    for (int i = threadIdx.x; i < nbkt; i += 256) {
        base[i] = atomicAdd(&bktCnt[i], cnt[i]);
        cnt[i] = 0;
    }
    __syncthreads();
    for (int e = elo + (int)threadIdx.x; e < ehi; e += 256) {
        int dst = load_idx32(ei32, is64, (long long)E + e);
        int src = load_idx32(ei32, is64, e);
        int b = dst >> BKT_SHIFT;
        int r = atomicAdd(&cnt[b], 1);
        bins[(size_t)b * cap + base[b] + r] =
            ((unsigned)(dst & (BKT_NODES - 1)) << 23) | (unsigned)src;
    }
}

// ---- bucketCSR: degree + local scan + scatter + dinv, one kernel ----
__global__ __launch_bounds__(256) void bucketCSR_kernel(
    const int* __restrict__ bktCnt, const unsigned* __restrict__ bins,
    int* __restrict__ off, int* __restrict__ offe, int* __restrict__ col,
    float* __restrict__ dinv, int N, int cap) {
    __shared__ int deg[BKT_NODES];
    __shared__ int loc[BKT_NODES];
    __shared__ int ssum[256];
    int b = blockIdx.x;
    int lo = b << BKT_SHIFT;
    int n = min(BKT_NODES, N - lo);
    for (int i = threadIdx.x; i < BKT_NODES; i += 256) deg[i] = 0;
    __syncthreads();
    int cnt = bktCnt[b];
    const unsigned* bb = bins + (size_t)b * cap;
    for (int i = threadIdx.x; i < cnt; i += 256)
        atomicAdd(&deg[bb[i] >> 23], 1);
    __syncthreads();
    int t = threadIdx.x;
    int d0 = deg[2 * t], d1 = deg[2 * t + 1];
    int s = d0 + d1;
    ssum[t] = s;
    __syncthreads();
    for (int o = 1; o < 256; o <<= 1) {
        int v = (t >= o) ? ssum[t - o] : 0;
        __syncthreads();
        ssum[t] += v;
        __syncthreads();
    }
    int excl = ssum[t] - s;
    loc[2 * t] = excl;
    loc[2 * t + 1] = excl + d0;
    __syncthreads();
    int base = b * cap;
    for (int i = threadIdx.x; i < n; i += 256) {
        int d = deg[i];
        off[lo + i] = base + loc[i];
        offe[lo + i] = base + loc[i] + d;
        dinv[lo + i] = 1.0f / fmaxf((float)d, 1.0f);
    }
    __syncthreads();
    for (int i = threadIdx.x; i < cnt; i += 256) {
        unsigned p = bb[i];
        int pos = atomicAdd(&loc[p >> 23], 1);
        col[base + pos] = (int)(p & 0x7FFFFFu);
    }
}

// ---- gather helper: one node's mean-agg into LDS (bf16) ----
__device__ __forceinline__ void gather_node(
    const unsigned short* __restrict__ Hhi, const int* __restrict__ off,
    const int* __restrict__ offe, const int* __restrict__ col,
    const float* __restrict__ dinv, unsigned short* __restrict__ aggRow,
    int n, int N, int g, int t16) {
    if (n >= N) {
        if (g == 0) {
            ushort4 z = {0, 0, 0, 0};
            *(ushort4*)&aggRow[t16 * 4] = z;
        }
        return;
    }
    int e = off[n], end = offe[n];
    float4 a0 = make_float4(0.f, 0.f, 0.f, 0.f);
    float4 a1 = make_float4(0.f, 0.f, 0.f, 0.f);
    float4 a2 = make_float4(0.f, 0.f, 0.f, 0.f);
    float4 a3 = make_float4(0.f, 0.f, 0.f, 0.f);
    for (; e + 16 <= end; e += 16) {
        int s0 = col[e + g];
        int s1 = col[e + 4 + g];
        int s2 = col[e + 8 + g];
        int s3 = col[e + 12 + g];
        ushort4 u0 = *(const ushort4*)&Hhi[(size_t)s0 * 64 + t16 * 4];
        ushort4 u1 = *(const ushort4*)&Hhi[(size_t)s1 * 64 + t16 * 4];
        ushort4 u2 = *(const ushort4*)&Hhi[(size_t)s2 * 64 + t16 * 4];
        ushort4 u3 = *(const ushort4*)&Hhi[(size_t)s3 * 64 + t16 * 4];
        a0.x += b2f(u0.x); a0.y += b2f(u0.y); a0.z += b2f(u0.z); a0.w += b2f(u0.w);
        a1.x += b2f(u1.x); a1.y += b2f(u1.y); a1.z += b2f(u1.z); a1.w += b2f(u1.w);
        a2.x += b2f(u2.x); a2.y += b2f(u2.y); a2.z += b2f(u2.z); a2.w += b2f(u2.w);
        a3.x += b2f(u3.x); a3.y += b2f(u3.y); a3.z += b2f(u3.z); a3.w += b2f(u3.w);
    }
    for (; e + 8 <= end; e += 8) {
        int s0 = col[e + g];
        int s1 = col[e + 4 + g];
        ushort4 u0 = *(const ushort4*)&Hhi[(size_t)s0 * 64 + t16 * 4];
        ushort4 u1 = *(const ushort4*)&Hhi[(size_t)s1 * 64 + t16 * 4];
        a0.x += b2f(u0.x); a0.y += b2f(u0.y); a0.z += b2f(u0.z); a0.w += b2f(u0.w);
        a1.x += b2f(u1.x); a1.y += b2f(u1.y); a1.z += b2f(u1.z); a1.w += b2f(u1.w);
    }
    for (; e < end; e += 4) {
        if (e + g < end) {
            int s0 = col[e + g];
            ushort4 u0 = *(const ushort4*)&Hhi[(size_t)s0 * 64 + t16 * 4];
            a2.x += b2f(u0.x); a2.y += b2f(u0.y); a2.z += b2f(u0.z); a2.w += b2f(u0.w);
        }
    }
    float4 acc;
    acc.x = (a0.x + a1.x) + (a2.x + a3.x);
    acc.y = (a0.y + a1.y) + (a2.y + a3.y);
    acc.z = (a0.z + a1.z) + (a2.z + a3.z);
    acc.w = (a0.w + a1.w) + (a2.w + a3.w);
#pragma unroll
    for (int msk = 16; msk <= 32; msk <<= 1) {
        acc.x += __shfl_xor(acc.x, msk, 64);
        acc.y += __shfl_xor(acc.y, msk, 64);
        acc.z += __shfl_xor(acc.z, msk, 64);
        acc.w += __shfl_xor(acc.w, msk, 64);
    }
    if (g == 0) {
        float di = dinv[n];
        ushort4 h;
        h.x = f2b_rne(acc.x * di);
        h.y = f2b_rne(acc.y * di);
        h.z = f2b_rne(acc.z * di);
        h.w = f2b_rne(acc.w * di);
        *(ushort4*)&aggRow[t16 * 4] = h;
    }
}

// ---- fused layer v2: block = 4 waves, 16 nodes; wave w gathers 4 nodes,
// then (after barrier) computes out-cols w*16..w*16+15 via MFMA. ----
__global__ __launch_bounds__(256) void layer_fused_kernel(
    const unsigned short* __restrict__ Hhi, const int* __restrict__ off,
    const int* __restrict__ offe, const int* __restrict__ col,
    const float* __restrict__ dinv,
    const unsigned short* __restrict__ Bthi, const unsigned short* __restrict__ Btlo,
    const float* __restrict__ b, unsigned short* __restrict__ Dhi, int N) {
    __shared__ unsigned short aggL[16 * AGG_STRIDE];
    int wave = threadIdx.x >> 6;
    int lane = threadIdx.x & 63;
    int g = lane >> 4;
    int t16 = lane & 15;
    int n0 = blockIdx.x * 16;
    // gather phase: wave w -> local nodes w*4..w*4+3
#pragma unroll
    for (int i = 0; i < 4; ++i) {
        int li = wave * 4 + i;
        gather_node(Hhi, off, offe, col, dinv, aggL + li * AGG_STRIDE,
                    n0 + li, N, g, t16);
    }
    __syncthreads();
    // dense phase: this wave owns out-cols wave*16 + m
    int m = t16, quad = g;
    int nr = n0 + m;
    if (nr > N - 1) nr = N - 1;
    const unsigned short* hrow = Hhi + (size_t)nr * 64 + quad * 8;
    bfrag ah[4];
    ah[0] = *(const bfrag*)(hrow);
    ah[1] = *(const bfrag*)(hrow + 32);
    ah[2] = *(const bfrag*)&aggL[m * AGG_STRIDE + quad * 8];
    ah[3] = *(const bfrag*)&aggL[m * AGG_STRIDE + 32 + quad * 8];
    int oc = wave * 16 + m;  // out col
    float bl = b[oc];
    ffrag acc = {bl, bl, bl, bl};
#pragma unroll
    for (int c = 0; c < 4; ++c) {
        bfrag bh = *(const bfrag*)(Bthi + (size_t)oc * 128 + c * 32 + quad * 8);
        bfrag bw = *(const bfrag*)(Btlo + (size_t)oc * 128 + c * 32 + quad * 8);
        acc = __builtin_amdgcn_mfma_f32_16x16x32_bf16(ah[c], bh, acc, 0, 0, 0);
        acc = __builtin_amdgcn_mfma_f32_16x16x32_bf16(ah[c], bw, acc, 0, 0, 0);
    }
#pragma unroll
    for (int r = 0; r < 4; ++r) {
        int node = n0 + quad * 4 + r;
        if (node < N)
            Dhi[(size_t)node * 64 + oc] = f2b_rne(fmaxf(acc[r], 0.f));
    }
}

// ---- fused layer 3 + layer-4 pre-transform ----
__global__ __launch_bounds__(256) void layer_fused_last_kernel(
    const unsigned short* __restrict__ Hhi, const int* __restrict__ off,
    const int* __restrict__ offe, const int* __restrict__ col,
    const float* __restrict__ dinv,
    const unsigned short* __restrict__ Bthi, const unsigned short* __restrict__ Btlo,
    const float* __restrict__ b, const float* __restrict__ Ws4,
    const float* __restrict__ Wn4, float* __restrict__ sbuf,
    float* __restrict__ gbuf, int N) {
    __shared__ unsigned short aggL[16 * AGG_STRIDE];
    __shared__ float sPart[4][16];
    __shared__ float gPart[4][16];
    int wave = threadIdx.x >> 6;
    int lane = threadIdx.x & 63;
    int g = lane >> 4;
    int t16 = lane & 15;
    int n0 = blockIdx.x * 16;
#pragma unroll
    for (int i = 0; i < 4; ++i) {
        int li = wave * 4 + i;
        gather_node(Hhi, off, offe, col, dinv, aggL + li * AGG_STRIDE,
                    n0 + li, N, g, t16);
    }
    __syncthreads();
    int m = t16, quad = g;
    int nr = n0 + m;
    if (nr > N - 1) nr = N - 1;
    const unsigned short* hrow = Hhi + (size_t)nr * 64 + quad * 8;
    bfrag ah[4];
    ah[0] = *(const bfrag*)(hrow);
    ah[1] = *(const bfrag*)(hrow + 32);
    ah[2] = *(const bfrag*)&aggL[m * AGG_STRIDE + quad * 8];
    ah[3] = *(const bfrag*)&aggL[m * AGG_STRIDE + 32 + quad * 8];
    int oc = wave * 16 + m;
    float bl = b[oc];
    ffrag acc = {bl, bl, bl, bl};
#pragma unroll
    for (int c = 0; c < 4; ++c) {
        bfrag bh = *(const bfrag*)(Bthi + (size_t)oc * 128 + c * 32 + quad * 8);
        bfrag bw = *(const bfrag*)(Btlo + (size_t)oc * 128 + c * 32 + quad * 8);
        acc = __builtin_amdgcn_mfma_f32_16x16x32_bf16(ah[c], bh, acc, 0, 0, 0);
        acc = __builtin_amdgcn_mfma_f32_16x16x32_bf16(ah[c], bw, acc, 0, 0, 0);
    }
    float w4s = Ws4[oc], w4n = Wn4[oc];
#pragma unroll
    for (int r = 0; r < 4; ++r) {
        float v = fmaxf(acc[r], 0.f);
        float ps = v * w4s;
        float pg = v * w4n;
#pragma unroll
        for (int mask = 1; mask <= 8; mask <<= 1) {
            ps += __shfl_xor(ps, mask, 64);
            pg += __shfl_xor(pg, mask, 64);
        }
        if (m == 0) {
            sPart[wave][quad * 4 + r] = ps;
            gPart[wave][quad * 4 + r] = pg;
        }
    }
    __syncthreads();
    if (threadIdx.x < 16) {
        int node = n0 + threadIdx.x;
        if (node < N) {
            float s = sPart[0][threadIdx.x] + sPart[1][threadIdx.x] +
                      sPart[2][threadIdx.x] + sPart[3][threadIdx.x];
            float gg = gPart[0][threadIdx.x] + gPart[1][threadIdx.x] +
                       gPart[2][threadIdx.x] + gPart[3][threadIdx.x];
            sbuf[node] = s;
            gbuf[node] = gg;
        }
    }
}

// thread per node: scalar CSR gather of g (400 KB, L2-resident) + sigmoid
__global__ void final_kernel(const float* __restrict__ s, const float* __restrict__ dinv,
                             const float* __restrict__ g, const int* __restrict__ off,
                             const int* __restrict__ offe, const int* __restrict__ col,
                             const float* __restrict__ b4, float* __restrict__ out, int N) {
    int n = blockIdx.x * blockDim.x + threadIdx.x;
    if (n >= N) return;
    float a = 0.f;
    int e = off[n], end = offe[n];
    for (; e < end; ++e) a += g[col[e]];
    float z = s[n] + dinv[n] * a + b4[0];
    out[n] = 1.0f / (1.0f + expf(-z));
}

static inline int cdiv(long long a, long long b) { return (int)((a + b - 1) / b); }

extern "C" void kernel_launch(void* const* d_in, const int* in_sizes, int n_in,
                              void* d_out, int out_size, void* d_ws, size_t ws_size,
                              hipStream_t stream) {
    const float* x   = (const float*)d_in[0];
    const int*   ei  = (const int*)d_in[1];
    const float* Ws1 = (const float*)d_in[2];
    const float* Wn1 = (const float*)d_in[3];
    const float* b1  = (const float*)d_in[4];
    const float* Ws2 = (const float*)d_in[5];
    const float* Wn2 = (const float*)d_in[6];
    const float* b2  = (const float*)d_in[7];
    const float* Ws3 = (const float*)d_in[8];
    const float* Wn3 = (const float*)d_in[9];
    const float* b3  = (const float*)d_in[10];
    const float* Ws4 = (const float*)d_in[11];
    const float* Wn4 = (const float*)d_in[12];
    const float* b4  = (const float*)d_in[13];
    float* out = (float*)d_out;

    const int N = in_sizes[0] / 64;
    const int E = in_sizes[1] / 2;

    const int nbkt = cdiv(N, BKT_NODES);                 // <=256
    const int cap  = E / nbkt + E / nbkt / 8 + 64;       // ~12.5% margin

    // workspace layout
    unsigned* bins = (unsigned*)d_ws;                    // nbkt*cap
    int* col = (int*)(bins + (size_t)nbkt * cap);        // nbkt*cap (bucket-local)
    unsigned short* HhiA = (unsigned short*)(col + (size_t)nbkt * cap);  // N*64
    unsigned short* HhiB = HhiA + (size_t)N * 64;        // N*64
    unsigned short* Bth  = HhiB + (size_t)N * 64;        // 3*8192
    unsigned short* Btl  = Bth + 3 * 8192;               // 3*8192
    float* dinv = (float*)(Btl + 3 * 8192);              // N
    float* sbuf = dinv + N;                              // N
    float* gbuf = sbuf + N;                              // N
    int*   off  = (int*)(gbuf + N);                      // N
    int*   offe = off + N;                               // N
    int*   bktc = offe + N;                              // 256
    int*   flag = bktc + 256;                            // 1

    const int BT = 256;
    const int gridN  = cdiv(N, BT);
    const int gridL  = cdiv(N, 16);                      // fused v2: 16 nodes/block
    const int binBlocks = 512;
    const int chunksz = cdiv(E, binBlocks);

    // ---- prep: weights + init, x->bf16 ----
    bprep_init_kernel<<<96, BT, 0, stream>>>(Ws1, Wn1, Ws2, Wn2, Ws3, Wn3,
                                             Bth, Btl, ei, bktc, flag);
    split_x_kernel<<<cdiv((long long)N * 16, BT), BT, 0, stream>>>(
        (const float4*)x, (ushort4*)HhiA, N * 16);

    // ---- CSR build: 2 kernels ----
    binA_kernel<<<binBlocks, BT, 0, stream>>>(ei, flag, bktc, bins, E, nbkt, cap, chunksz);
    bucketCSR_kernel<<<nbkt, BT, 0, stream>>>(bktc, bins, off, offe, col, dinv, N, cap);

    // ---- layers 1-3 (fused gather+dense v2) ----
    layer_fused_kernel<<<gridL, BT, 0, stream>>>(HhiA, off, offe, col, dinv,
                                                 Bth, Btl, b1, HhiB, N);
    layer_fused_kernel<<<gridL, BT, 0, stream>>>(HhiB, off, offe, col, dinv,
                                                 Bth + 8192, Btl + 8192, b2, HhiA, N);
    layer_fused_last_kernel<<<gridL, BT, 0, stream>>>(HhiA, off, offe, col, dinv,
                                                      Bth + 16384, Btl + 16384, b3,
                                                      Ws4, Wn4, sbuf, gbuf, N);

    // ---- layer 4 (64->1): scalar CSR gather + sigmoid ----
    final_kernel<<<gridN, BT, 0, stream>>>(sbuf, dinv, gbuf, off, offe, col, b4, out, N);
}